// Round 1
// baseline (3136.285 us; speedup 1.0000x reference)
//
#include <hip/hip_runtime.h>
#include <math.h>

#define N_NODES 50000
#define N_EDGES 1600000
#define DIM_IN  128
#define DIM_HID 64
#define NHEADS  8
#define HDIM    (NHEADS*DIM_HID)   // 512
#define DIM_OUT 128

// ---------- helpers ----------
__device__ __forceinline__ unsigned enc_max(float f) {
  unsigned b = __float_as_uint(f);
  return (b & 0x80000000u) ? ~b : (b | 0x80000000u);
}
__device__ __forceinline__ float dec_max(unsigned u) {
  unsigned b = (u & 0x80000000u) ? (u & 0x7fffffffu) : ~u;
  return __uint_as_float(b);
}
__device__ __forceinline__ float leaky(float x) { return x >= 0.f ? x : 0.2f * x; }

// ---------- pack W_heads [8][128][64] -> Wpack [128][512] ----------
__global__ void pack_w_heads(const float* __restrict__ Wh, float* __restrict__ Wp) {
  int idx = blockIdx.x * 256 + threadIdx.x;
  if (idx >= DIM_IN * HDIM) return;
  int k = idx >> 9;          // /512
  int n = idx & 511;
  int h = n >> 6, j = n & 63;
  Wp[idx] = Wh[h * (DIM_IN * DIM_HID) + k * DIM_HID + j];
}

// ---------- generic fp32 GEMM: C[M,N] = A[M,K] @ B[K,N] (+bias[N]) ----------
// BM=BN=128, BK=16, 256 threads, 8x8 per thread. N%128==0, K%16==0 assumed.
__global__ __launch_bounds__(256) void gemm_f32(
    const float* __restrict__ A, const float* __restrict__ B,
    float* __restrict__ C, const float* __restrict__ bias,
    int M, int N, int K) {
  __shared__ float As[16][132];
  __shared__ float Bs[16][132];
  const int tid = threadIdx.x;
  const int tx = tid & 15, ty = tid >> 4;
  const int m0 = blockIdx.y * 128, n0 = blockIdx.x * 128;
  float acc[8][8];
#pragma unroll
  for (int i = 0; i < 8; ++i)
#pragma unroll
    for (int j = 0; j < 8; ++j) acc[i][j] = 0.f;

  for (int k0 = 0; k0 < K; k0 += 16) {
#pragma unroll
    for (int q = 0; q < 2; ++q) {             // A tile 128x16, transposed store
      int f4 = tid + q * 256;
      int row = f4 >> 2;
      int c4 = (f4 & 3) << 2;
      int gr = m0 + row;
      float4 v = make_float4(0.f, 0.f, 0.f, 0.f);
      if (gr < M) v = *reinterpret_cast<const float4*>(&A[(size_t)gr * K + k0 + c4]);
      As[c4 + 0][row] = v.x; As[c4 + 1][row] = v.y;
      As[c4 + 2][row] = v.z; As[c4 + 3][row] = v.w;
    }
#pragma unroll
    for (int q = 0; q < 2; ++q) {             // B tile 16x128
      int f4 = tid + q * 256;
      int row = f4 >> 5;
      int c4 = (f4 & 31) << 2;
      float4 v = *reinterpret_cast<const float4*>(&B[(size_t)(k0 + row) * N + n0 + c4]);
      *reinterpret_cast<float4*>(&Bs[row][c4]) = v;
    }
    __syncthreads();
#pragma unroll
    for (int kk = 0; kk < 16; ++kk) {
      float a[8], b[8];
#pragma unroll
      for (int i = 0; i < 8; ++i) a[i] = As[kk][ty * 8 + i];
#pragma unroll
      for (int j = 0; j < 8; ++j) b[j] = Bs[kk][tx * 8 + j];
#pragma unroll
      for (int i = 0; i < 8; ++i)
#pragma unroll
        for (int j = 0; j < 8; ++j) acc[i][j] = fmaf(a[i], b[j], acc[i][j]);
    }
    __syncthreads();
  }
  const int gc = n0 + tx * 8;
  float bb[8];
#pragma unroll
  for (int j = 0; j < 8; ++j) bb[j] = bias ? bias[gc + j] : 0.f;
#pragma unroll
  for (int i = 0; i < 8; ++i) {
    int gr = m0 + ty * 8 + i;
    if (gr >= M) continue;
    float4 v0, v1;
    v0.x = acc[i][0] + bb[0]; v0.y = acc[i][1] + bb[1];
    v0.z = acc[i][2] + bb[2]; v0.w = acc[i][3] + bb[3];
    v1.x = acc[i][4] + bb[4]; v1.y = acc[i][5] + bb[5];
    v1.z = acc[i][6] + bb[6]; v1.w = acc[i][7] + bb[7];
    *reinterpret_cast<float4*>(&C[(size_t)gr * N + gc]) = v0;
    *reinterpret_cast<float4*>(&C[(size_t)gr * N + gc + 4]) = v1;
  }
}

// ---------- attention projections, layer 1: wave per node ----------
__global__ __launch_bounds__(256) void attn1_kernel(
    const float* __restrict__ msg, const float* __restrict__ a_heads,
    float* __restrict__ asrc, float* __restrict__ adst, int Nn) {
  int lane = threadIdx.x & 63;
  int n = blockIdx.x * 4 + (threadIdx.x >> 6);
  if (n >= Nn) return;
#pragma unroll
  for (int h = 0; h < NHEADS; ++h) {
    float v = msg[(size_t)n * HDIM + h * 64 + lane];
    float s = v * a_heads[h * 128 + lane];
    float d = v * a_heads[h * 128 + 64 + lane];
#pragma unroll
    for (int off = 32; off; off >>= 1) {
      s += __shfl_xor(s, off, 64);
      d += __shfl_xor(d, off, 64);
    }
    if (lane == 0) { asrc[n * 8 + h] = s; adst[n * 8 + h] = d; }
  }
}

// ---------- attention projections, layer 2 ----------
__global__ __launch_bounds__(256) void attn2_kernel(
    const float* __restrict__ msg, const float* __restrict__ a_out,
    float* __restrict__ asrc, float* __restrict__ adst, int Nn) {
  int lane = threadIdx.x & 63;
  int n = blockIdx.x * 4 + (threadIdx.x >> 6);
  if (n >= Nn) return;
  float v0 = msg[(size_t)n * 128 + lane];
  float v1 = msg[(size_t)n * 128 + 64 + lane];
  float s = v0 * a_out[lane] + v1 * a_out[64 + lane];
  float d = v0 * a_out[128 + lane] + v1 * a_out[192 + lane];
#pragma unroll
  for (int off = 32; off; off >>= 1) {
    s += __shfl_xor(s, off, 64);
    d += __shfl_xor(d, off, 64);
  }
  if (lane == 0) { asrc[n] = s; adst[n] = d; }
}

// ---------- CSR build ----------
__global__ void hist_kernel(const int* __restrict__ edst, int* __restrict__ counts, int E) {
  for (int e = blockIdx.x * blockDim.x + threadIdx.x; e < E; e += gridDim.x * blockDim.x)
    atomicAdd(&counts[edst[e]], 1);
}

__global__ __launch_bounds__(1024) void scan_kernel(
    const int* __restrict__ counts, int* __restrict__ rowptr, int n) {
  __shared__ int tmp[1024];
  __shared__ int carry_sh;
  int tid = threadIdx.x;
  if (tid == 0) carry_sh = 0;
  __syncthreads();
  for (int base = 0; base < n; base += 1024) {
    int i = base + tid;
    int v = (i < n) ? counts[i] : 0;
    tmp[tid] = v;
    __syncthreads();
    int x = v;
    for (int off = 1; off < 1024; off <<= 1) {
      int t = (tid >= off) ? tmp[tid - off] : 0;
      __syncthreads();
      x += t;
      tmp[tid] = x;
      __syncthreads();
    }
    int carry = carry_sh;
    if (i < n) rowptr[i] = carry + x - v;   // exclusive
    int total = tmp[1023];
    __syncthreads();
    if (tid == 0) carry_sh = carry + total;
    __syncthreads();
  }
  if (tid == 0) rowptr[n] = carry_sh;
}

__global__ void scatter_kernel(const int* __restrict__ edst, const int* __restrict__ rowptr,
                               int* __restrict__ cursor, int* __restrict__ colidx, int E) {
  for (int e = blockIdx.x * blockDim.x + threadIdx.x; e < E; e += gridDim.x * blockDim.x) {
    int d = edst[e];
    int pos = rowptr[d] + atomicAdd(&cursor[d], 1);
    colidx[pos] = e;
  }
}

// ---------- global score max, layer 1 (8 heads) ----------
__global__ void max1_kernel(const int* __restrict__ esrc, const int* __restrict__ edst,
                            const float* __restrict__ asrc, const float* __restrict__ adst,
                            unsigned* __restrict__ maxbuf, int E) {
  float m[8];
#pragma unroll
  for (int h = 0; h < 8; ++h) m[h] = -3.4e38f;
  for (int e = blockIdx.x * blockDim.x + threadIdx.x; e < E; e += gridDim.x * blockDim.x) {
    int s = esrc[e], d = edst[e];
    float4 s0 = *reinterpret_cast<const float4*>(&asrc[(size_t)s * 8]);
    float4 s1 = *reinterpret_cast<const float4*>(&asrc[(size_t)s * 8 + 4]);
    float4 d0 = *reinterpret_cast<const float4*>(&adst[(size_t)d * 8]);
    float4 d1 = *reinterpret_cast<const float4*>(&adst[(size_t)d * 8 + 4]);
    float xs[8] = {s0.x + d0.x, s0.y + d0.y, s0.z + d0.z, s0.w + d0.w,
                   s1.x + d1.x, s1.y + d1.y, s1.z + d1.z, s1.w + d1.w};
#pragma unroll
    for (int h = 0; h < 8; ++h) m[h] = fmaxf(m[h], leaky(xs[h]));
  }
#pragma unroll
  for (int h = 0; h < 8; ++h)
#pragma unroll
    for (int off = 32; off; off >>= 1) m[h] = fmaxf(m[h], __shfl_xor(m[h], off, 64));
  if ((threadIdx.x & 63) == 0)
#pragma unroll
    for (int h = 0; h < 8; ++h) atomicMax(&maxbuf[h], enc_max(m[h]));
}

// ---------- denom (segment sum of exp), layer 1 ----------
__global__ void denom1_kernel(const int* __restrict__ esrc, const int* __restrict__ edst,
                              const float* __restrict__ asrc, const float* __restrict__ adst,
                              const unsigned* __restrict__ maxbuf, float* __restrict__ denom, int E) {
  float mx[8];
#pragma unroll
  for (int h = 0; h < 8; ++h) mx[h] = dec_max(maxbuf[h]);
  for (int e = blockIdx.x * blockDim.x + threadIdx.x; e < E; e += gridDim.x * blockDim.x) {
    int s = esrc[e], d = edst[e];
    float4 s0 = *reinterpret_cast<const float4*>(&asrc[(size_t)s * 8]);
    float4 s1 = *reinterpret_cast<const float4*>(&asrc[(size_t)s * 8 + 4]);
    float4 d0 = *reinterpret_cast<const float4*>(&adst[(size_t)d * 8]);
    float4 d1 = *reinterpret_cast<const float4*>(&adst[(size_t)d * 8 + 4]);
    float xs[8] = {s0.x + d0.x, s0.y + d0.y, s0.z + d0.z, s0.w + d0.w,
                   s1.x + d1.x, s1.y + d1.y, s1.z + d1.z, s1.w + d1.w};
#pragma unroll
    for (int h = 0; h < 8; ++h)
      atomicAdd(&denom[(size_t)d * 8 + h], __expf(leaky(xs[h]) - mx[h]));
  }
}

// ---------- layer-1 aggregation: block(128) per node, float4 per thread ----------
__global__ __launch_bounds__(128) void agg1_kernel(
    const float* __restrict__ msg, const float* __restrict__ asrc,
    const float* __restrict__ adst, const float* __restrict__ denom,
    const unsigned* __restrict__ maxbuf, const int* __restrict__ rowptr,
    const int* __restrict__ colidx, const int* __restrict__ esrc,
    float* __restrict__ out) {
  int n = blockIdx.x;
  int tid = threadIdx.x;
  __shared__ int s_sh[64];
  __shared__ float coef_sh[64][8];
  __shared__ float hdr[24];  // [0..7] max, [8..15] adst, [16..23] 1/denom
  if (tid < 8) {
    hdr[tid] = dec_max(maxbuf[tid]);
    hdr[8 + tid] = adst[(size_t)n * 8 + tid];
    hdr[16 + tid] = 1.0f / (denom[(size_t)n * 8 + tid] + 1e-10f);
  }
  __syncthreads();
  const int h = tid >> 4;                     // (tid*4)/64
  const int e0 = rowptr[n], e1 = rowptr[n + 1];
  float4 acc = make_float4(0.f, 0.f, 0.f, 0.f);
  for (int base = e0; base < e1; base += 64) {
    int cnt = min(64, e1 - base);
    __syncthreads();
#pragma unroll
    for (int q = 0; q < 4; ++q) {
      int slot = q * 128 + tid;               // 512 slots = 64 edges x 8 heads
      int el = slot >> 3, hh = slot & 7;
      if (el < cnt) {
        int eid = colidx[base + el];
        int s = esrc[eid];
        if (hh == 0) s_sh[el] = s;
        float x = asrc[(size_t)s * 8 + hh] + hdr[8 + hh];
        x = x >= 0.f ? x : 0.2f * x;
        coef_sh[el][hh] = __expf(x - hdr[hh]) * hdr[16 + hh];
      }
    }
    __syncthreads();
    for (int e = 0; e < cnt; ++e) {
      int s = s_sh[e];
      float c = coef_sh[e][h];
      float4 m4 = *reinterpret_cast<const float4*>(&msg[(size_t)s * HDIM + tid * 4]);
      acc.x = fmaf(m4.x, c, acc.x);
      acc.y = fmaf(m4.y, c, acc.y);
      acc.z = fmaf(m4.z, c, acc.z);
      acc.w = fmaf(m4.w, c, acc.w);
    }
  }
  *reinterpret_cast<float4*>(&out[(size_t)n * HDIM + tid * 4]) = acc;
}

// ---------- layer-2 max / denom / aggregation (single head) ----------
__global__ void max2_kernel(const int* __restrict__ esrc, const int* __restrict__ edst,
                            const float* __restrict__ asrc, const float* __restrict__ adst,
                            unsigned* __restrict__ maxbuf, int E) {
  float m = -3.4e38f;
  for (int e = blockIdx.x * blockDim.x + threadIdx.x; e < E; e += gridDim.x * blockDim.x) {
    float x = asrc[esrc[e]] + adst[edst[e]];
    m = fmaxf(m, leaky(x));
  }
#pragma unroll
  for (int off = 32; off; off >>= 1) m = fmaxf(m, __shfl_xor(m, off, 64));
  if ((threadIdx.x & 63) == 0) atomicMax(maxbuf, enc_max(m));
}

__global__ void denom2_kernel(const int* __restrict__ esrc, const int* __restrict__ edst,
                              const float* __restrict__ asrc, const float* __restrict__ adst,
                              const unsigned* __restrict__ maxbuf, float* __restrict__ denom, int E) {
  float mx = dec_max(maxbuf[0]);
  for (int e = blockIdx.x * blockDim.x + threadIdx.x; e < E; e += gridDim.x * blockDim.x) {
    int d = edst[e];
    float x = asrc[esrc[e]] + adst[d];
    atomicAdd(&denom[d], __expf(leaky(x) - mx));
  }
}

__global__ __launch_bounds__(128) void agg2_kernel(
    const float* __restrict__ msg, const float* __restrict__ asrc,
    const float* __restrict__ adst, const float* __restrict__ denom,
    const unsigned* __restrict__ maxbuf, const int* __restrict__ rowptr,
    const int* __restrict__ colidx, const int* __restrict__ esrc,
    float* __restrict__ out) {
  int n = blockIdx.x;
  int tid = threadIdx.x;
  __shared__ int s_sh[64];
  __shared__ float coef_sh[64];
  float maxv = dec_max(maxbuf[0]);
  float ad = adst[n];
  float dinv = 1.0f / (denom[n] + 1e-10f);
  int e0 = rowptr[n], e1 = rowptr[n + 1];
  float acc = 0.f;
  for (int base = e0; base < e1; base += 64) {
    int cnt = min(64, e1 - base);
    __syncthreads();
    if (tid < cnt) {
      int eid = colidx[base + tid];
      int s = esrc[eid];
      s_sh[tid] = s;
      float x = asrc[s] + ad;
      x = x >= 0.f ? x : 0.2f * x;
      coef_sh[tid] = __expf(x - maxv) * dinv;
    }
    __syncthreads();
    for (int e = 0; e < cnt; ++e)
      acc = fmaf(msg[(size_t)s_sh[e] * 128 + tid], coef_sh[e], acc);
  }
  out[(size_t)n * 128 + tid] = acc;
}

// ---------- BN statistics ----------
__global__ void colstats_kernel(const float* __restrict__ X, float* __restrict__ sums,
                                float* __restrict__ sqs, int M, int C, int rowsPerBlock) {
  int c = blockIdx.x * blockDim.x + threadIdx.x;
  if (c >= C) return;
  int r0 = blockIdx.y * rowsPerBlock;
  int r1 = min(M, r0 + rowsPerBlock);
  float s = 0.f, s2 = 0.f;
  for (int r = r0; r < r1; ++r) {
    float v = X[(size_t)r * C + c];
    s += v; s2 = fmaf(v, v, s2);
  }
  atomicAdd(&sums[c], s);
  atomicAdd(&sqs[c], s2);
}

__global__ void bnparams_kernel(const float* __restrict__ sums, const float* __restrict__ sqs,
                                const float* __restrict__ gamma, const float* __restrict__ beta,
                                float* __restrict__ scale, float* __restrict__ shift,
                                int C, float invM) {
  int c = blockIdx.x * blockDim.x + threadIdx.x;
  if (c >= C) return;
  float mean = sums[c] * invM;
  float var = sqs[c] * invM - mean * mean;
  float inv = rsqrtf(var + 1e-5f);
  float sc = gamma[c] * inv;
  scale[c] = sc;
  shift[c] = beta[c] - mean * sc;
}

// ---------- fold layer-1 BN into W_out ----------
__global__ void foldw2_kernel(const float* __restrict__ W, const float* __restrict__ scale,
                              float* __restrict__ Wp) {
  int idx = blockIdx.x * 256 + threadIdx.x;
  if (idx >= HDIM * DIM_OUT) return;
  int c = idx >> 7;
  Wp[idx] = W[idx] * scale[c];
}

__global__ void bias2_kernel(const float* __restrict__ W, const float* __restrict__ shift,
                             float* __restrict__ bias2) {
  int j = threadIdx.x;
  if (j >= DIM_OUT) return;
  float s = 0.f;
  for (int c = 0; c < HDIM; ++c) s = fmaf(shift[c], W[c * DIM_OUT + j], s);
  bias2[j] = s;
}

// ---------- final: BN(out2) + residual ----------
__global__ void final_kernel(float* __restrict__ out, const float* __restrict__ resid,
                             const float* __restrict__ scale, const float* __restrict__ shift,
                             int total) {
  for (int i = blockIdx.x * blockDim.x + threadIdx.x; i < total; i += gridDim.x * blockDim.x) {
    int c = i & 127;
    out[i] = fmaf(out[i], scale[c], shift[c]) + resid[i];
  }
}

// ==================== host ====================
extern "C" void kernel_launch(void* const* d_in, const int* in_sizes, int n_in,
                              void* d_out, int out_size, void* d_ws, size_t ws_size,
                              hipStream_t stream) {
  const float* feat    = (const float*)d_in[0];
  const int*   edges   = (const int*)d_in[1];
  const int*   esrc    = edges;
  const int*   edst    = edges + N_EDGES;
  const float* W_heads = (const float*)d_in[2];
  const float* a_heads = (const float*)d_in[3];
  const float* gamma_h = (const float*)d_in[4];
  const float* beta_h  = (const float*)d_in[5];
  const float* W_out   = (const float*)d_in[6];
  const float* a_out   = (const float*)d_in[7];
  const float* gamma_o = (const float*)d_in[8];
  const float* beta_o  = (const float*)d_in[9];
  const float* W_res   = (const float*)d_in[10];
  const float* b_res   = (const float*)d_in[11];
  float* out = (float*)d_out;

  char* ws = (char*)d_ws;
  size_t off = 0;
  auto alloc = [&](size_t bytes) {
    void* p = ws + off;
    off = (off + bytes + 255) & ~(size_t)255;
    return p;
  };
  float*    msg1   = (float*)alloc((size_t)N_NODES * HDIM * 4);   // reused as msg2
  float*    out1   = (float*)alloc((size_t)N_NODES * HDIM * 4);   // reused as resid
  float*    asrc1  = (float*)alloc((size_t)N_NODES * NHEADS * 4); // reused as asrc2
  float*    adst1  = (float*)alloc((size_t)N_NODES * NHEADS * 4); // reused as adst2
  float*    denom1 = (float*)alloc((size_t)N_NODES * NHEADS * 4); // reused as denom2
  int*      counts = (int*)alloc((size_t)N_NODES * 4);
  int*      cursor = (int*)alloc((size_t)N_NODES * 4);
  int*      rowptr = (int*)alloc((size_t)(N_NODES + 1) * 4);
  int*      colidx = (int*)alloc((size_t)N_EDGES * 4);
  unsigned* maxbuf = (unsigned*)alloc(64);                        // [0..7] L1, [8] L2
  float*    colsum = (float*)alloc(HDIM * 4);
  float*    colsq  = (float*)alloc(HDIM * 4);
  float*    scale1 = (float*)alloc(HDIM * 4);
  float*    shift1 = (float*)alloc(HDIM * 4);
  float*    scale2 = (float*)alloc(DIM_OUT * 4);
  float*    shift2 = (float*)alloc(DIM_OUT * 4);
  float*    Wpack  = (float*)alloc((size_t)DIM_IN * HDIM * 4);
  float*    W2p    = (float*)alloc((size_t)HDIM * DIM_OUT * 4);
  float*    bias2  = (float*)alloc(DIM_OUT * 4);
  float* msg2 = msg1;
  float* resid = out1;
  float* asrc2 = asrc1; float* adst2 = adst1; float* denom2 = denom1;
  (void)n_in; (void)in_sizes; (void)out_size; (void)ws_size;

  // zero-init accumulators
  hipMemsetAsync(counts, 0, (size_t)N_NODES * 4, stream);
  hipMemsetAsync(cursor, 0, (size_t)N_NODES * 4, stream);
  hipMemsetAsync(denom1, 0, (size_t)N_NODES * NHEADS * 4, stream);
  hipMemsetAsync(maxbuf, 0, 64, stream);
  hipMemsetAsync(colsum, 0, HDIM * 4, stream);
  hipMemsetAsync(colsq, 0, HDIM * 4, stream);

  // ---- layer 1 ----
  pack_w_heads<<<(DIM_IN * HDIM + 255) / 256, 256, 0, stream>>>(W_heads, Wpack);
  dim3 g1(HDIM / 128, (N_NODES + 127) / 128);
  gemm_f32<<<g1, 256, 0, stream>>>(feat, Wpack, msg1, nullptr, N_NODES, HDIM, DIM_IN);
  attn1_kernel<<<(N_NODES + 3) / 4, 256, 0, stream>>>(msg1, a_heads, asrc1, adst1, N_NODES);

  hist_kernel<<<2048, 256, 0, stream>>>(edst, counts, N_EDGES);
  scan_kernel<<<1, 1024, 0, stream>>>(counts, rowptr, N_NODES);
  scatter_kernel<<<2048, 256, 0, stream>>>(edst, rowptr, cursor, colidx, N_EDGES);

  max1_kernel<<<2048, 256, 0, stream>>>(esrc, edst, asrc1, adst1, maxbuf, N_EDGES);
  denom1_kernel<<<2048, 256, 0, stream>>>(esrc, edst, asrc1, adst1, maxbuf, denom1, N_EDGES);
  agg1_kernel<<<N_NODES, 128, 0, stream>>>(msg1, asrc1, adst1, denom1, maxbuf,
                                           rowptr, colidx, esrc, out1);

  colstats_kernel<<<dim3(HDIM / 128, 98), 128, 0, stream>>>(out1, colsum, colsq, N_NODES, HDIM, 512);
  bnparams_kernel<<<(HDIM + 127) / 128, 128, 0, stream>>>(colsum, colsq, gamma_h, beta_h,
                                                          scale1, shift1, HDIM, 1.0f / N_NODES);
  foldw2_kernel<<<(HDIM * DIM_OUT + 255) / 256, 256, 0, stream>>>(W_out, scale1, W2p);
  bias2_kernel<<<1, 128, 0, stream>>>(W_out, shift1, bias2);

  // ---- layer 2 ----
  dim3 g2(DIM_OUT / 128, (N_NODES + 127) / 128);
  gemm_f32<<<g2, 256, 0, stream>>>(out1, W2p, msg2, bias2, N_NODES, DIM_OUT, HDIM);
  attn2_kernel<<<(N_NODES + 3) / 4, 256, 0, stream>>>(msg2, a_out, asrc2, adst2, N_NODES);

  hipMemsetAsync(denom2, 0, (size_t)N_NODES * 4, stream);
  max2_kernel<<<2048, 256, 0, stream>>>(esrc, edst, asrc2, adst2, maxbuf + 8, N_EDGES);
  denom2_kernel<<<2048, 256, 0, stream>>>(esrc, edst, asrc2, adst2, maxbuf + 8, denom2, N_EDGES);
  agg2_kernel<<<N_NODES, 128, 0, stream>>>(msg2, asrc2, adst2, denom2, maxbuf + 8,
                                           rowptr, colidx, esrc, out);

  // residual GEMM (out1 dead after gemm2)
  gemm_f32<<<g2, 256, 0, stream>>>(feat, W_res, resid, b_res, N_NODES, DIM_OUT, DIM_IN);

  // layer-2 BN + residual
  hipMemsetAsync(colsum, 0, HDIM * 4, stream);
  hipMemsetAsync(colsq, 0, HDIM * 4, stream);
  colstats_kernel<<<dim3(1, 98), 128, 0, stream>>>(out, colsum, colsq, N_NODES, DIM_OUT, 512);
  bnparams_kernel<<<1, 128, 0, stream>>>(colsum, colsq, gamma_o, beta_o,
                                         scale2, shift2, DIM_OUT, 1.0f / N_NODES);
  final_kernel<<<2048, 256, 0, stream>>>(out, resid, scale2, shift2, N_NODES * DIM_OUT);
}

// Round 2
// 1539.574 us; speedup vs baseline: 2.0371x; 2.0371x over previous
//
#include <hip/hip_runtime.h>
#include <math.h>

#define N_NODES 50000
#define N_EDGES 1600000
#define DIM_IN  128
#define DIM_HID 64
#define NHEADS  8
#define HDIM    (NHEADS*DIM_HID)   // 512
#define DIM_OUT 128
#define MAXBLK  512                // blocks for edge-max partial pass

__device__ __forceinline__ float leaky(float x) { return x >= 0.f ? x : 0.2f * x; }

// ---------- pack W_heads [8][128][64] -> Wpack [128][512] ----------
__global__ void pack_w_heads(const float* __restrict__ Wh, float* __restrict__ Wp) {
  int idx = blockIdx.x * 256 + threadIdx.x;
  if (idx >= DIM_IN * HDIM) return;
  int k = idx >> 9;          // /512
  int n = idx & 511;
  int h = n >> 6, j = n & 63;
  Wp[idx] = Wh[h * (DIM_IN * DIM_HID) + k * DIM_HID + j];
}

// ---------- generic fp32 GEMM: C[M,N] = A[M,K] @ B[K,N] (+bias[N]) ----------
__global__ __launch_bounds__(256) void gemm_f32(
    const float* __restrict__ A, const float* __restrict__ B,
    float* __restrict__ C, const float* __restrict__ bias,
    int M, int N, int K) {
  __shared__ float As[16][132];
  __shared__ float Bs[16][132];
  const int tid = threadIdx.x;
  const int tx = tid & 15, ty = tid >> 4;
  const int m0 = blockIdx.y * 128, n0 = blockIdx.x * 128;
  float acc[8][8];
#pragma unroll
  for (int i = 0; i < 8; ++i)
#pragma unroll
    for (int j = 0; j < 8; ++j) acc[i][j] = 0.f;

  for (int k0 = 0; k0 < K; k0 += 16) {
#pragma unroll
    for (int q = 0; q < 2; ++q) {             // A tile 128x16, transposed store
      int f4 = tid + q * 256;
      int row = f4 >> 2;
      int c4 = (f4 & 3) << 2;
      int gr = m0 + row;
      float4 v = make_float4(0.f, 0.f, 0.f, 0.f);
      if (gr < M) v = *reinterpret_cast<const float4*>(&A[(size_t)gr * K + k0 + c4]);
      As[c4 + 0][row] = v.x; As[c4 + 1][row] = v.y;
      As[c4 + 2][row] = v.z; As[c4 + 3][row] = v.w;
    }
#pragma unroll
    for (int q = 0; q < 2; ++q) {             // B tile 16x128
      int f4 = tid + q * 256;
      int row = f4 >> 5;
      int c4 = (f4 & 31) << 2;
      float4 v = *reinterpret_cast<const float4*>(&B[(size_t)(k0 + row) * N + n0 + c4]);
      *reinterpret_cast<float4*>(&Bs[row][c4]) = v;
    }
    __syncthreads();
#pragma unroll
    for (int kk = 0; kk < 16; ++kk) {
      float a[8], b[8];
#pragma unroll
      for (int i = 0; i < 8; ++i) a[i] = As[kk][ty * 8 + i];
#pragma unroll
      for (int j = 0; j < 8; ++j) b[j] = Bs[kk][tx * 8 + j];
#pragma unroll
      for (int i = 0; i < 8; ++i)
#pragma unroll
        for (int j = 0; j < 8; ++j) acc[i][j] = fmaf(a[i], b[j], acc[i][j]);
    }
    __syncthreads();
  }
  const int gc = n0 + tx * 8;
  float bb[8];
#pragma unroll
  for (int j = 0; j < 8; ++j) bb[j] = bias ? bias[gc + j] : 0.f;
#pragma unroll
  for (int i = 0; i < 8; ++i) {
    int gr = m0 + ty * 8 + i;
    if (gr >= M) continue;
    float4 v0, v1;
    v0.x = acc[i][0] + bb[0]; v0.y = acc[i][1] + bb[1];
    v0.z = acc[i][2] + bb[2]; v0.w = acc[i][3] + bb[3];
    v1.x = acc[i][4] + bb[4]; v1.y = acc[i][5] + bb[5];
    v1.z = acc[i][6] + bb[6]; v1.w = acc[i][7] + bb[7];
    *reinterpret_cast<float4*>(&C[(size_t)gr * N + gc]) = v0;
    *reinterpret_cast<float4*>(&C[(size_t)gr * N + gc + 4]) = v1;
  }
}

// ---------- attention projections, layer 1: wave per node ----------
__global__ __launch_bounds__(256) void attn1_kernel(
    const float* __restrict__ msg, const float* __restrict__ a_heads,
    float* __restrict__ asrc, float* __restrict__ adst, int Nn) {
  int lane = threadIdx.x & 63;
  int n = blockIdx.x * 4 + (threadIdx.x >> 6);
  if (n >= Nn) return;
#pragma unroll
  for (int h = 0; h < NHEADS; ++h) {
    float v = msg[(size_t)n * HDIM + h * 64 + lane];
    float s = v * a_heads[h * 128 + lane];
    float d = v * a_heads[h * 128 + 64 + lane];
#pragma unroll
    for (int off = 32; off; off >>= 1) {
      s += __shfl_xor(s, off, 64);
      d += __shfl_xor(d, off, 64);
    }
    if (lane == 0) { asrc[n * 8 + h] = s; adst[n * 8 + h] = d; }
  }
}

// ---------- attention projections, layer 2 ----------
__global__ __launch_bounds__(256) void attn2_kernel(
    const float* __restrict__ msg, const float* __restrict__ a_out,
    float* __restrict__ asrc, float* __restrict__ adst, int Nn) {
  int lane = threadIdx.x & 63;
  int n = blockIdx.x * 4 + (threadIdx.x >> 6);
  if (n >= Nn) return;
  float v0 = msg[(size_t)n * 128 + lane];
  float v1 = msg[(size_t)n * 128 + 64 + lane];
  float s = v0 * a_out[lane] + v1 * a_out[64 + lane];
  float d = v0 * a_out[128 + lane] + v1 * a_out[192 + lane];
#pragma unroll
  for (int off = 32; off; off >>= 1) {
    s += __shfl_xor(s, off, 64);
    d += __shfl_xor(d, off, 64);
  }
  if (lane == 0) { asrc[n] = s; adst[n] = d; }
}

// ---------- CSR build ----------
__global__ void hist_kernel(const int* __restrict__ edst, int* __restrict__ counts, int E) {
  for (int e = blockIdx.x * blockDim.x + threadIdx.x; e < E; e += gridDim.x * blockDim.x)
    atomicAdd(&counts[edst[e]], 1);
}

__global__ __launch_bounds__(1024) void scan_kernel(
    const int* __restrict__ counts, int* __restrict__ rowptr, int n) {
  __shared__ int tmp[1024];
  __shared__ int carry_sh;
  int tid = threadIdx.x;
  if (tid == 0) carry_sh = 0;
  __syncthreads();
  for (int base = 0; base < n; base += 1024) {
    int i = base + tid;
    int v = (i < n) ? counts[i] : 0;
    tmp[tid] = v;
    __syncthreads();
    int x = v;
    for (int off = 1; off < 1024; off <<= 1) {
      int t = (tid >= off) ? tmp[tid - off] : 0;
      __syncthreads();
      x += t;
      tmp[tid] = x;
      __syncthreads();
    }
    int carry = carry_sh;
    if (i < n) rowptr[i] = carry + x - v;   // exclusive
    int total = tmp[1023];
    __syncthreads();
    if (tid == 0) carry_sh = carry + total;
    __syncthreads();
  }
  if (tid == 0) rowptr[n] = carry_sh;
}

// scatter: store the SOURCE node id directly (one less indirection in agg)
__global__ void scatter_kernel(const int* __restrict__ esrc, const int* __restrict__ edst,
                               const int* __restrict__ rowptr, int* __restrict__ cursor,
                               int* __restrict__ colsrc, int E) {
  for (int e = blockIdx.x * blockDim.x + threadIdx.x; e < E; e += gridDim.x * blockDim.x) {
    int d = edst[e];
    int pos = rowptr[d] + atomicAdd(&cursor[d], 1);
    colsrc[pos] = esrc[e];
  }
}

// ---------- global score max, layer 1: two-stage, NO global atomics ----------
__global__ __launch_bounds__(256) void max1_part_kernel(
    const int* __restrict__ esrc, const int* __restrict__ edst,
    const float* __restrict__ asrc, const float* __restrict__ adst,
    float* __restrict__ part, int E) {
  float m[8];
#pragma unroll
  for (int h = 0; h < 8; ++h) m[h] = -3.4e38f;
  for (int e = blockIdx.x * blockDim.x + threadIdx.x; e < E; e += gridDim.x * blockDim.x) {
    int s = esrc[e], d = edst[e];
    float4 s0 = *reinterpret_cast<const float4*>(&asrc[(size_t)s * 8]);
    float4 s1 = *reinterpret_cast<const float4*>(&asrc[(size_t)s * 8 + 4]);
    float4 d0 = *reinterpret_cast<const float4*>(&adst[(size_t)d * 8]);
    float4 d1 = *reinterpret_cast<const float4*>(&adst[(size_t)d * 8 + 4]);
    float xs[8] = {s0.x + d0.x, s0.y + d0.y, s0.z + d0.z, s0.w + d0.w,
                   s1.x + d1.x, s1.y + d1.y, s1.z + d1.z, s1.w + d1.w};
#pragma unroll
    for (int h = 0; h < 8; ++h) m[h] = fmaxf(m[h], leaky(xs[h]));
  }
#pragma unroll
  for (int h = 0; h < 8; ++h)
#pragma unroll
    for (int off = 32; off; off >>= 1) m[h] = fmaxf(m[h], __shfl_xor(m[h], off, 64));
  __shared__ float sm[4][8];
  int wv = threadIdx.x >> 6, ln = threadIdx.x & 63;
  if (ln == 0)
#pragma unroll
    for (int h = 0; h < 8; ++h) sm[wv][h] = m[h];
  __syncthreads();
  if (threadIdx.x < 8) {
    int h = threadIdx.x;
    part[blockIdx.x * 8 + h] =
        fmaxf(fmaxf(sm[0][h], sm[1][h]), fmaxf(sm[2][h], sm[3][h]));
  }
}

__global__ void max1_final_kernel(const float* __restrict__ part, float* __restrict__ maxv, int nblk) {
  int t = threadIdx.x;            // 64 threads
  int h = t & 7, k = t >> 3;
  float m = -3.4e38f;
  for (int i = k; i < nblk; i += 8) m = fmaxf(m, part[i * 8 + h]);
  m = fmaxf(m, __shfl_xor(m, 8, 64));
  m = fmaxf(m, __shfl_xor(m, 16, 64));
  m = fmaxf(m, __shfl_xor(m, 32, 64));
  if (t < 8) maxv[t] = m;
}

// ---------- layer-2 max, two-stage ----------
__global__ __launch_bounds__(256) void max2_part_kernel(
    const int* __restrict__ esrc, const int* __restrict__ edst,
    const float* __restrict__ asrc, const float* __restrict__ adst,
    float* __restrict__ part, int E) {
  float m = -3.4e38f;
  for (int e = blockIdx.x * blockDim.x + threadIdx.x; e < E; e += gridDim.x * blockDim.x) {
    float x = asrc[esrc[e]] + adst[edst[e]];
    m = fmaxf(m, leaky(x));
  }
#pragma unroll
  for (int off = 32; off; off >>= 1) m = fmaxf(m, __shfl_xor(m, off, 64));
  __shared__ float sm[4];
  int wv = threadIdx.x >> 6, ln = threadIdx.x & 63;
  if (ln == 0) sm[wv] = m;
  __syncthreads();
  if (threadIdx.x == 0)
    part[blockIdx.x] = fmaxf(fmaxf(sm[0], sm[1]), fmaxf(sm[2], sm[3]));
}

__global__ void max2_final_kernel(const float* __restrict__ part, float* __restrict__ maxv, int nblk) {
  int t = threadIdx.x;            // 64 threads
  float m = -3.4e38f;
  for (int i = t; i < nblk; i += 64) m = fmaxf(m, part[i]);
#pragma unroll
  for (int off = 32; off; off >>= 1) m = fmaxf(m, __shfl_xor(m, off, 64));
  if (t == 0) maxv[0] = m;
}

// ---------- layer-1 aggregation with fused denominator ----------
__global__ __launch_bounds__(128) void agg1_kernel(
    const float* __restrict__ msg, const float* __restrict__ asrc,
    const float* __restrict__ adst, const float* __restrict__ maxv,
    const int* __restrict__ rowptr, const int* __restrict__ colsrc,
    float* __restrict__ out) {
  int n = blockIdx.x;
  int tid = threadIdx.x;
  __shared__ int s_sh[64];
  __shared__ float coef_sh[64][8];
  __shared__ float hdr[16];  // [0..7] max, [8..15] adst
  if (tid < 8) {
    hdr[tid] = maxv[tid];
    hdr[8 + tid] = adst[(size_t)n * 8 + tid];
  }
  __syncthreads();
  const int h = tid >> 4;                     // (tid*4)/64
  const int e0 = rowptr[n], e1 = rowptr[n + 1];
  float4 acc = make_float4(0.f, 0.f, 0.f, 0.f);
  float dsum = 0.f;
  for (int base = e0; base < e1; base += 64) {
    int cnt = min(64, e1 - base);
    __syncthreads();
#pragma unroll
    for (int q = 0; q < 4; ++q) {
      int slot = q * 128 + tid;               // 512 slots = 64 edges x 8 heads
      int el = slot >> 3, hh = slot & 7;
      if (el < cnt) {
        int s = colsrc[base + el];
        if (hh == 0) s_sh[el] = s;
        float x = asrc[(size_t)s * 8 + hh] + hdr[8 + hh];
        x = x >= 0.f ? x : 0.2f * x;
        coef_sh[el][hh] = __expf(x - hdr[hh]);   // un-normalized
      }
    }
    __syncthreads();
    for (int e = 0; e < cnt; ++e) {
      int s = s_sh[e];
      float c = coef_sh[e][h];
      dsum += c;
      float4 m4 = *reinterpret_cast<const float4*>(&msg[(size_t)s * HDIM + tid * 4]);
      acc.x = fmaf(m4.x, c, acc.x);
      acc.y = fmaf(m4.y, c, acc.y);
      acc.z = fmaf(m4.z, c, acc.z);
      acc.w = fmaf(m4.w, c, acc.w);
    }
  }
  float inv = 1.0f / (dsum + 1e-10f);
  float4 r;
  r.x = acc.x * inv; r.y = acc.y * inv; r.z = acc.z * inv; r.w = acc.w * inv;
  *reinterpret_cast<float4*>(&out[(size_t)n * HDIM + tid * 4]) = r;
}

// ---------- layer-2 aggregation with fused denominator ----------
__global__ __launch_bounds__(128) void agg2_kernel(
    const float* __restrict__ msg, const float* __restrict__ asrc,
    const float* __restrict__ adst, const float* __restrict__ maxv,
    const int* __restrict__ rowptr, const int* __restrict__ colsrc,
    float* __restrict__ out) {
  int n = blockIdx.x;
  int tid = threadIdx.x;
  __shared__ int s_sh[64];
  __shared__ float coef_sh[64];
  float M = maxv[0];
  float ad = adst[n];
  int e0 = rowptr[n], e1 = rowptr[n + 1];
  float acc = 0.f, dsum = 0.f;
  for (int base = e0; base < e1; base += 64) {
    int cnt = min(64, e1 - base);
    __syncthreads();
    if (tid < cnt) {
      int s = colsrc[base + tid];
      s_sh[tid] = s;
      float x = asrc[s] + ad;
      x = x >= 0.f ? x : 0.2f * x;
      coef_sh[tid] = __expf(x - M);
    }
    __syncthreads();
    for (int e = 0; e < cnt; ++e) {
      float c = coef_sh[e];
      dsum += c;
      acc = fmaf(msg[(size_t)s_sh[e] * 128 + tid], c, acc);
    }
  }
  out[(size_t)n * 128 + tid] = acc / (dsum + 1e-10f);
}

// ---------- BN statistics ----------
__global__ void colstats_kernel(const float* __restrict__ X, float* __restrict__ sums,
                                float* __restrict__ sqs, int M, int C, int rowsPerBlock) {
  int c = blockIdx.x * blockDim.x + threadIdx.x;
  if (c >= C) return;
  int r0 = blockIdx.y * rowsPerBlock;
  int r1 = min(M, r0 + rowsPerBlock);
  float s = 0.f, s2 = 0.f;
  for (int r = r0; r < r1; ++r) {
    float v = X[(size_t)r * C + c];
    s += v; s2 = fmaf(v, v, s2);
  }
  atomicAdd(&sums[c], s);
  atomicAdd(&sqs[c], s2);
}

__global__ void bnparams_kernel(const float* __restrict__ sums, const float* __restrict__ sqs,
                                const float* __restrict__ gamma, const float* __restrict__ beta,
                                float* __restrict__ scale, float* __restrict__ shift,
                                int C, float invM) {
  int c = blockIdx.x * blockDim.x + threadIdx.x;
  if (c >= C) return;
  float mean = sums[c] * invM;
  float var = sqs[c] * invM - mean * mean;
  float inv = rsqrtf(var + 1e-5f);
  float sc = gamma[c] * inv;
  scale[c] = sc;
  shift[c] = beta[c] - mean * sc;
}

// ---------- fold layer-1 BN into W_out ----------
__global__ void foldw2_kernel(const float* __restrict__ W, const float* __restrict__ scale,
                              float* __restrict__ Wp) {
  int idx = blockIdx.x * 256 + threadIdx.x;
  if (idx >= HDIM * DIM_OUT) return;
  int c = idx >> 7;
  Wp[idx] = W[idx] * scale[c];
}

__global__ void bias2_kernel(const float* __restrict__ W, const float* __restrict__ shift,
                             float* __restrict__ bias2) {
  int j = threadIdx.x;
  if (j >= DIM_OUT) return;
  float s = 0.f;
  for (int c = 0; c < HDIM; ++c) s = fmaf(shift[c], W[c * DIM_OUT + j], s);
  bias2[j] = s;
}

// ---------- final: BN(out2) + residual ----------
__global__ void final_kernel(float* __restrict__ out, const float* __restrict__ resid,
                             const float* __restrict__ scale, const float* __restrict__ shift,
                             int total) {
  for (int i = blockIdx.x * blockDim.x + threadIdx.x; i < total; i += gridDim.x * blockDim.x) {
    int c = i & 127;
    out[i] = fmaf(out[i], scale[c], shift[c]) + resid[i];
  }
}

// ==================== host ====================
extern "C" void kernel_launch(void* const* d_in, const int* in_sizes, int n_in,
                              void* d_out, int out_size, void* d_ws, size_t ws_size,
                              hipStream_t stream) {
  const float* feat    = (const float*)d_in[0];
  const int*   edges   = (const int*)d_in[1];
  const int*   esrc    = edges;
  const int*   edst    = edges + N_EDGES;
  const float* W_heads = (const float*)d_in[2];
  const float* a_heads = (const float*)d_in[3];
  const float* gamma_h = (const float*)d_in[4];
  const float* beta_h  = (const float*)d_in[5];
  const float* W_out   = (const float*)d_in[6];
  const float* a_out   = (const float*)d_in[7];
  const float* gamma_o = (const float*)d_in[8];
  const float* beta_o  = (const float*)d_in[9];
  const float* W_res   = (const float*)d_in[10];
  const float* b_res   = (const float*)d_in[11];
  float* out = (float*)d_out;

  char* ws = (char*)d_ws;
  size_t off = 0;
  auto alloc = [&](size_t bytes) {
    void* p = ws + off;
    off = (off + bytes + 255) & ~(size_t)255;
    return p;
  };
  float*    msg1   = (float*)alloc((size_t)N_NODES * HDIM * 4);   // reused as msg2
  float*    out1   = (float*)alloc((size_t)N_NODES * HDIM * 4);   // reused as resid
  float*    asrc1  = (float*)alloc((size_t)N_NODES * NHEADS * 4); // reused as asrc2
  float*    adst1  = (float*)alloc((size_t)N_NODES * NHEADS * 4); // reused as adst2
  int*      counts = (int*)alloc((size_t)N_NODES * 4);
  int*      cursor = (int*)alloc((size_t)N_NODES * 4);
  int*      rowptr = (int*)alloc((size_t)(N_NODES + 1) * 4);
  int*      colsrc = (int*)alloc((size_t)N_EDGES * 4);
  float*    part   = (float*)alloc((size_t)MAXBLK * 8 * 4);
  float*    maxv1  = (float*)alloc(8 * 4);
  float*    maxv2  = (float*)alloc(4);
  float*    colsum = (float*)alloc(HDIM * 4);
  float*    colsq  = (float*)alloc(HDIM * 4);
  float*    scale1 = (float*)alloc(HDIM * 4);
  float*    shift1 = (float*)alloc(HDIM * 4);
  float*    scale2 = (float*)alloc(DIM_OUT * 4);
  float*    shift2 = (float*)alloc(DIM_OUT * 4);
  float*    Wpack  = (float*)alloc((size_t)DIM_IN * HDIM * 4);
  float*    W2p    = (float*)alloc((size_t)HDIM * DIM_OUT * 4);
  float*    bias2  = (float*)alloc(DIM_OUT * 4);
  float* msg2 = msg1;
  float* resid = out1;
  float* asrc2 = asrc1; float* adst2 = adst1;
  (void)n_in; (void)in_sizes; (void)out_size; (void)ws_size;

  hipMemsetAsync(counts, 0, (size_t)N_NODES * 4, stream);
  hipMemsetAsync(cursor, 0, (size_t)N_NODES * 4, stream);
  hipMemsetAsync(colsum, 0, HDIM * 4, stream);
  hipMemsetAsync(colsq, 0, HDIM * 4, stream);

  // ---- layer 1 ----
  pack_w_heads<<<(DIM_IN * HDIM + 255) / 256, 256, 0, stream>>>(W_heads, Wpack);
  dim3 g1(HDIM / 128, (N_NODES + 127) / 128);
  gemm_f32<<<g1, 256, 0, stream>>>(feat, Wpack, msg1, nullptr, N_NODES, HDIM, DIM_IN);
  attn1_kernel<<<(N_NODES + 3) / 4, 256, 0, stream>>>(msg1, a_heads, asrc1, adst1, N_NODES);

  hist_kernel<<<2048, 256, 0, stream>>>(edst, counts, N_EDGES);
  scan_kernel<<<1, 1024, 0, stream>>>(counts, rowptr, N_NODES);
  scatter_kernel<<<2048, 256, 0, stream>>>(esrc, edst, rowptr, cursor, colsrc, N_EDGES);

  max1_part_kernel<<<MAXBLK, 256, 0, stream>>>(esrc, edst, asrc1, adst1, part, N_EDGES);
  max1_final_kernel<<<1, 64, 0, stream>>>(part, maxv1, MAXBLK);
  agg1_kernel<<<N_NODES, 128, 0, stream>>>(msg1, asrc1, adst1, maxv1, rowptr, colsrc, out1);

  colstats_kernel<<<dim3(HDIM / 128, 98), 128, 0, stream>>>(out1, colsum, colsq, N_NODES, HDIM, 512);
  bnparams_kernel<<<(HDIM + 127) / 128, 128, 0, stream>>>(colsum, colsq, gamma_h, beta_h,
                                                          scale1, shift1, HDIM, 1.0f / N_NODES);
  foldw2_kernel<<<(HDIM * DIM_OUT + 255) / 256, 256, 0, stream>>>(W_out, scale1, W2p);
  bias2_kernel<<<1, 128, 0, stream>>>(W_out, shift1, bias2);

  // ---- layer 2 ----
  dim3 g2(DIM_OUT / 128, (N_NODES + 127) / 128);
  gemm_f32<<<g2, 256, 0, stream>>>(out1, W2p, msg2, bias2, N_NODES, DIM_OUT, HDIM);
  attn2_kernel<<<(N_NODES + 3) / 4, 256, 0, stream>>>(msg2, a_out, asrc2, adst2, N_NODES);

  max2_part_kernel<<<MAXBLK, 256, 0, stream>>>(esrc, edst, asrc2, adst2, part, N_EDGES);
  max2_final_kernel<<<1, 64, 0, stream>>>(part, maxv2, MAXBLK);
  agg2_kernel<<<N_NODES, 128, 0, stream>>>(msg2, asrc2, adst2, maxv2, rowptr, colsrc, out);

  // residual GEMM (out1 dead after gemm2)
  gemm_f32<<<g2, 256, 0, stream>>>(feat, W_res, resid, b_res, N_NODES, DIM_OUT, DIM_IN);

  // layer-2 BN + residual
  hipMemsetAsync(colsum, 0, HDIM * 4, stream);
  hipMemsetAsync(colsq, 0, HDIM * 4, stream);
  colstats_kernel<<<dim3(1, 98), 128, 0, stream>>>(out, colsum, colsq, N_NODES, DIM_OUT, 512);
  bnparams_kernel<<<1, 128, 0, stream>>>(colsum, colsq, gamma_o, beta_o,
                                         scale2, shift2, DIM_OUT, 1.0f / N_NODES);
  final_kernel<<<2048, 256, 0, stream>>>(out, resid, scale2, shift2, N_NODES * DIM_OUT);
}

// Round 3
// 1186.503 us; speedup vs baseline: 2.6433x; 1.2976x over previous
//
#include <hip/hip_runtime.h>
#include <math.h>

#define N_NODES 50000
#define N_EDGES 1600000
#define DIM_IN  128
#define DIM_HID 64
#define NHEADS  8
#define HDIM    (NHEADS*DIM_HID)   // 512
#define DIM_OUT 128
#define MAXBLK  512

typedef __attribute__((ext_vector_type(2))) unsigned short us2;
typedef __attribute__((ext_vector_type(4))) unsigned short us4;
typedef __attribute__((ext_vector_type(8))) unsigned short us8;

__device__ __forceinline__ float leaky(float x) { return x >= 0.f ? x : 0.2f * x; }
__device__ __forceinline__ float bf2f(unsigned short h) {
  return __uint_as_float(((unsigned)h) << 16);
}
__device__ __forceinline__ unsigned short f2bf(float f) {
  unsigned u = __float_as_uint(f);
  unsigned r = (u + 0x7fffu + ((u >> 16) & 1u)) >> 16;
  return (unsigned short)r;
}

// ---------- pack W_heads [8][128][64] -> Wpack [128][512] ----------
__global__ void pack_w_heads(const float* __restrict__ Wh, float* __restrict__ Wp) {
  int idx = blockIdx.x * 256 + threadIdx.x;
  if (idx >= DIM_IN * HDIM) return;
  int k = idx >> 9;
  int n = idx & 511;
  int h = n >> 6, j = n & 63;
  Wp[idx] = Wh[h * (DIM_IN * DIM_HID) + k * DIM_HID + j];
}

// ---------- fp32 GEMM, fp32 out: C[M,N] = A@B (+bias) ----------
__global__ __launch_bounds__(256) void gemm_f32(
    const float* __restrict__ A, const float* __restrict__ B,
    float* __restrict__ C, const float* __restrict__ bias,
    int M, int N, int K) {
  __shared__ float As[16][132];
  __shared__ float Bs[16][132];
  const int tid = threadIdx.x;
  const int tx = tid & 15, ty = tid >> 4;
  const int m0 = blockIdx.y * 128, n0 = blockIdx.x * 128;
  float acc[8][8];
#pragma unroll
  for (int i = 0; i < 8; ++i)
#pragma unroll
    for (int j = 0; j < 8; ++j) acc[i][j] = 0.f;

  for (int k0 = 0; k0 < K; k0 += 16) {
#pragma unroll
    for (int q = 0; q < 2; ++q) {
      int f4 = tid + q * 256;
      int row = f4 >> 2;
      int c4 = (f4 & 3) << 2;
      int gr = m0 + row;
      float4 v = make_float4(0.f, 0.f, 0.f, 0.f);
      if (gr < M) v = *reinterpret_cast<const float4*>(&A[(size_t)gr * K + k0 + c4]);
      As[c4 + 0][row] = v.x; As[c4 + 1][row] = v.y;
      As[c4 + 2][row] = v.z; As[c4 + 3][row] = v.w;
    }
#pragma unroll
    for (int q = 0; q < 2; ++q) {
      int f4 = tid + q * 256;
      int row = f4 >> 5;
      int c4 = (f4 & 31) << 2;
      float4 v = *reinterpret_cast<const float4*>(&B[(size_t)(k0 + row) * N + n0 + c4]);
      *reinterpret_cast<float4*>(&Bs[row][c4]) = v;
    }
    __syncthreads();
#pragma unroll
    for (int kk = 0; kk < 16; ++kk) {
      float a[8], b[8];
#pragma unroll
      for (int i = 0; i < 8; ++i) a[i] = As[kk][ty * 8 + i];
#pragma unroll
      for (int j = 0; j < 8; ++j) b[j] = Bs[kk][tx * 8 + j];
#pragma unroll
      for (int i = 0; i < 8; ++i)
#pragma unroll
        for (int j = 0; j < 8; ++j) acc[i][j] = fmaf(a[i], b[j], acc[i][j]);
    }
    __syncthreads();
  }
  const int gc = n0 + tx * 8;
  float bb[8];
#pragma unroll
  for (int j = 0; j < 8; ++j) bb[j] = bias ? bias[gc + j] : 0.f;
#pragma unroll
  for (int i = 0; i < 8; ++i) {
    int gr = m0 + ty * 8 + i;
    if (gr >= M) continue;
    float4 v0, v1;
    v0.x = acc[i][0] + bb[0]; v0.y = acc[i][1] + bb[1];
    v0.z = acc[i][2] + bb[2]; v0.w = acc[i][3] + bb[3];
    v1.x = acc[i][4] + bb[4]; v1.y = acc[i][5] + bb[5];
    v1.z = acc[i][6] + bb[6]; v1.w = acc[i][7] + bb[7];
    *reinterpret_cast<float4*>(&C[(size_t)gr * N + gc]) = v0;
    *reinterpret_cast<float4*>(&C[(size_t)gr * N + gc + 4]) = v1;
  }
}

// ---------- fp32 GEMM, bf16 out ----------
__global__ __launch_bounds__(256) void gemm_bf(
    const float* __restrict__ A, const float* __restrict__ B,
    unsigned short* __restrict__ C, const float* __restrict__ bias,
    int M, int N, int K) {
  __shared__ float As[16][132];
  __shared__ float Bs[16][132];
  const int tid = threadIdx.x;
  const int tx = tid & 15, ty = tid >> 4;
  const int m0 = blockIdx.y * 128, n0 = blockIdx.x * 128;
  float acc[8][8];
#pragma unroll
  for (int i = 0; i < 8; ++i)
#pragma unroll
    for (int j = 0; j < 8; ++j) acc[i][j] = 0.f;

  for (int k0 = 0; k0 < K; k0 += 16) {
#pragma unroll
    for (int q = 0; q < 2; ++q) {
      int f4 = tid + q * 256;
      int row = f4 >> 2;
      int c4 = (f4 & 3) << 2;
      int gr = m0 + row;
      float4 v = make_float4(0.f, 0.f, 0.f, 0.f);
      if (gr < M) v = *reinterpret_cast<const float4*>(&A[(size_t)gr * K + k0 + c4]);
      As[c4 + 0][row] = v.x; As[c4 + 1][row] = v.y;
      As[c4 + 2][row] = v.z; As[c4 + 3][row] = v.w;
    }
#pragma unroll
    for (int q = 0; q < 2; ++q) {
      int f4 = tid + q * 256;
      int row = f4 >> 5;
      int c4 = (f4 & 31) << 2;
      float4 v = *reinterpret_cast<const float4*>(&B[(size_t)(k0 + row) * N + n0 + c4]);
      *reinterpret_cast<float4*>(&Bs[row][c4]) = v;
    }
    __syncthreads();
#pragma unroll
    for (int kk = 0; kk < 16; ++kk) {
      float a[8], b[8];
#pragma unroll
      for (int i = 0; i < 8; ++i) a[i] = As[kk][ty * 8 + i];
#pragma unroll
      for (int j = 0; j < 8; ++j) b[j] = Bs[kk][tx * 8 + j];
#pragma unroll
      for (int i = 0; i < 8; ++i)
#pragma unroll
        for (int j = 0; j < 8; ++j) acc[i][j] = fmaf(a[i], b[j], acc[i][j]);
    }
    __syncthreads();
  }
  const int gc = n0 + tx * 8;
  float bb[8];
#pragma unroll
  for (int j = 0; j < 8; ++j) bb[j] = bias ? bias[gc + j] : 0.f;
#pragma unroll
  for (int i = 0; i < 8; ++i) {
    int gr = m0 + ty * 8 + i;
    if (gr >= M) continue;
    us8 o;
#pragma unroll
    for (int j = 0; j < 8; ++j) o[j] = f2bf(acc[i][j] + bb[j]);
    *reinterpret_cast<us8*>(&C[(size_t)gr * N + gc]) = o;
  }
}

// ---------- attn projections layer 1 (bf16 msg) ----------
__global__ __launch_bounds__(256) void attn1_kernel(
    const unsigned short* __restrict__ msg, const float* __restrict__ a_heads,
    float* __restrict__ asrc, float* __restrict__ adst, int Nn) {
  int lane = threadIdx.x & 63;
  int n = blockIdx.x * 4 + (threadIdx.x >> 6);
  if (n >= Nn) return;
  us8 v = *reinterpret_cast<const us8*>(&msg[(size_t)n * HDIM + lane * 8]);
  int h = lane >> 3, p0 = (lane & 7) * 8;
  float s = 0.f, d = 0.f;
#pragma unroll
  for (int j = 0; j < 8; ++j) {
    float f = bf2f(v[j]);
    s = fmaf(f, a_heads[h * 128 + p0 + j], s);
    d = fmaf(f, a_heads[h * 128 + 64 + p0 + j], d);
  }
  s += __shfl_xor(s, 1, 64); s += __shfl_xor(s, 2, 64); s += __shfl_xor(s, 4, 64);
  d += __shfl_xor(d, 1, 64); d += __shfl_xor(d, 2, 64); d += __shfl_xor(d, 4, 64);
  if ((lane & 7) == 0) { asrc[n * 8 + h] = s; adst[n * 8 + h] = d; }
}

// ---------- attn projections layer 2 (bf16 msg) ----------
__global__ __launch_bounds__(256) void attn2_kernel(
    const unsigned short* __restrict__ msg, const float* __restrict__ a_out,
    float* __restrict__ asrc, float* __restrict__ adst, int Nn) {
  int lane = threadIdx.x & 63;
  int n = blockIdx.x * 4 + (threadIdx.x >> 6);
  if (n >= Nn) return;
  us2 v = *reinterpret_cast<const us2*>(&msg[(size_t)n * 128 + lane * 2]);
  float f0 = bf2f(v[0]), f1 = bf2f(v[1]);
  float s = f0 * a_out[2 * lane] + f1 * a_out[2 * lane + 1];
  float d = f0 * a_out[128 + 2 * lane] + f1 * a_out[128 + 2 * lane + 1];
#pragma unroll
  for (int off = 32; off; off >>= 1) {
    s += __shfl_xor(s, off, 64);
    d += __shfl_xor(d, off, 64);
  }
  if (lane == 0) { asrc[n] = s; adst[n] = d; }
}

// ---------- CSR build ----------
__global__ void hist_kernel(const int* __restrict__ edst, int* __restrict__ counts, int E) {
  for (int e = blockIdx.x * blockDim.x + threadIdx.x; e < E; e += gridDim.x * blockDim.x)
    atomicAdd(&counts[edst[e]], 1);
}

__global__ __launch_bounds__(1024) void scan_kernel(
    const int* __restrict__ counts, int* __restrict__ rowptr, int n) {
  __shared__ int tmp[1024];
  __shared__ int carry_sh;
  int tid = threadIdx.x;
  if (tid == 0) carry_sh = 0;
  __syncthreads();
  for (int base = 0; base < n; base += 1024) {
    int i = base + tid;
    int v = (i < n) ? counts[i] : 0;
    tmp[tid] = v;
    __syncthreads();
    int x = v;
    for (int off = 1; off < 1024; off <<= 1) {
      int t = (tid >= off) ? tmp[tid - off] : 0;
      __syncthreads();
      x += t;
      tmp[tid] = x;
      __syncthreads();
    }
    int carry = carry_sh;
    if (i < n) rowptr[i] = carry + x - v;
    int total = tmp[1023];
    __syncthreads();
    if (tid == 0) carry_sh = carry + total;
    __syncthreads();
  }
  if (tid == 0) rowptr[n] = carry_sh;
}

__global__ void scatter_kernel(const int* __restrict__ esrc, const int* __restrict__ edst,
                               const int* __restrict__ rowptr, int* __restrict__ cursor,
                               int* __restrict__ colsrc, int E) {
  for (int e = blockIdx.x * blockDim.x + threadIdx.x; e < E; e += gridDim.x * blockDim.x) {
    int d = edst[e];
    int pos = rowptr[d] + atomicAdd(&cursor[d], 1);
    colsrc[pos] = esrc[e];
  }
}

// ---------- layer-1 max, two-stage ----------
__global__ __launch_bounds__(256) void max1_part_kernel(
    const int* __restrict__ esrc, const int* __restrict__ edst,
    const float* __restrict__ asrc, const float* __restrict__ adst,
    float* __restrict__ part, int E) {
  float m[8];
#pragma unroll
  for (int h = 0; h < 8; ++h) m[h] = -3.4e38f;
  for (int e = blockIdx.x * blockDim.x + threadIdx.x; e < E; e += gridDim.x * blockDim.x) {
    int s = esrc[e], d = edst[e];
    float4 s0 = *reinterpret_cast<const float4*>(&asrc[(size_t)s * 8]);
    float4 s1 = *reinterpret_cast<const float4*>(&asrc[(size_t)s * 8 + 4]);
    float4 d0 = *reinterpret_cast<const float4*>(&adst[(size_t)d * 8]);
    float4 d1 = *reinterpret_cast<const float4*>(&adst[(size_t)d * 8 + 4]);
    float xs[8] = {s0.x + d0.x, s0.y + d0.y, s0.z + d0.z, s0.w + d0.w,
                   s1.x + d1.x, s1.y + d1.y, s1.z + d1.z, s1.w + d1.w};
#pragma unroll
    for (int h = 0; h < 8; ++h) m[h] = fmaxf(m[h], leaky(xs[h]));
  }
#pragma unroll
  for (int h = 0; h < 8; ++h)
#pragma unroll
    for (int off = 32; off; off >>= 1) m[h] = fmaxf(m[h], __shfl_xor(m[h], off, 64));
  __shared__ float sm[4][8];
  int wv = threadIdx.x >> 6, ln = threadIdx.x & 63;
  if (ln == 0)
#pragma unroll
    for (int h = 0; h < 8; ++h) sm[wv][h] = m[h];
  __syncthreads();
  if (threadIdx.x < 8) {
    int h = threadIdx.x;
    part[blockIdx.x * 8 + h] =
        fmaxf(fmaxf(sm[0][h], sm[1][h]), fmaxf(sm[2][h], sm[3][h]));
  }
}

__global__ void max1_final_kernel(const float* __restrict__ part, float* __restrict__ maxv, int nblk) {
  int t = threadIdx.x;
  int h = t & 7, k = t >> 3;
  float m = -3.4e38f;
  for (int i = k; i < nblk; i += 8) m = fmaxf(m, part[i * 8 + h]);
  m = fmaxf(m, __shfl_xor(m, 8, 64));
  m = fmaxf(m, __shfl_xor(m, 16, 64));
  m = fmaxf(m, __shfl_xor(m, 32, 64));
  if (t < 8) maxv[t] = m;
}

// ---------- layer-2 max, two-stage ----------
__global__ __launch_bounds__(256) void max2_part_kernel(
    const int* __restrict__ esrc, const int* __restrict__ edst,
    const float* __restrict__ asrc, const float* __restrict__ adst,
    float* __restrict__ part, int E) {
  float m = -3.4e38f;
  for (int e = blockIdx.x * blockDim.x + threadIdx.x; e < E; e += gridDim.x * blockDim.x) {
    float x = asrc[esrc[e]] + adst[edst[e]];
    m = fmaxf(m, leaky(x));
  }
#pragma unroll
  for (int off = 32; off; off >>= 1) m = fmaxf(m, __shfl_xor(m, off, 64));
  __shared__ float sm[4];
  int wv = threadIdx.x >> 6, ln = threadIdx.x & 63;
  if (ln == 0) sm[wv] = m;
  __syncthreads();
  if (threadIdx.x == 0)
    part[blockIdx.x] = fmaxf(fmaxf(sm[0], sm[1]), fmaxf(sm[2], sm[3]));
}

__global__ void max2_final_kernel(const float* __restrict__ part, float* __restrict__ maxv, int nblk) {
  int t = threadIdx.x;
  float m = -3.4e38f;
  for (int i = t; i < nblk; i += 64) m = fmaxf(m, part[i]);
#pragma unroll
  for (int off = 32; off; off >>= 1) m = fmaxf(m, __shfl_xor(m, off, 64));
  if (t == 0) maxv[0] = m;
}

// ---------- layer-1 aggregation (bf16 msg, fused denom) ----------
__global__ __launch_bounds__(128) void agg1_kernel(
    const unsigned short* __restrict__ msg, const float* __restrict__ asrc,
    const float* __restrict__ adst, const float* __restrict__ maxv,
    const int* __restrict__ rowptr, const int* __restrict__ colsrc,
    float* __restrict__ out) {
  int n = blockIdx.x;
  int tid = threadIdx.x;
  __shared__ int s_sh[64];
  __shared__ float coef_sh[64][8];
  __shared__ float hdr[16];
  if (tid < 8) {
    hdr[tid] = maxv[tid];
    hdr[8 + tid] = adst[(size_t)n * 8 + tid];
  }
  __syncthreads();
  const int h = tid >> 4;
  const int e0 = rowptr[n], e1 = rowptr[n + 1];
  float4 acc = make_float4(0.f, 0.f, 0.f, 0.f);
  float dsum = 0.f;
  for (int base = e0; base < e1; base += 64) {
    int cnt = min(64, e1 - base);
    __syncthreads();
#pragma unroll
    for (int q = 0; q < 4; ++q) {
      int slot = q * 128 + tid;
      int el = slot >> 3, hh = slot & 7;
      if (el < cnt) {
        int s = colsrc[base + el];
        if (hh == 0) s_sh[el] = s;
        float x = asrc[(size_t)s * 8 + hh] + hdr[8 + hh];
        x = x >= 0.f ? x : 0.2f * x;
        coef_sh[el][hh] = __expf(x - hdr[hh]);
      }
    }
    __syncthreads();
    for (int e = 0; e < cnt; ++e) {
      int s = s_sh[e];
      float c = coef_sh[e][h];
      dsum += c;
      us4 m4 = *reinterpret_cast<const us4*>(&msg[(size_t)s * HDIM + tid * 4]);
      acc.x = fmaf(bf2f(m4[0]), c, acc.x);
      acc.y = fmaf(bf2f(m4[1]), c, acc.y);
      acc.z = fmaf(bf2f(m4[2]), c, acc.z);
      acc.w = fmaf(bf2f(m4[3]), c, acc.w);
    }
  }
  float inv = 1.0f / (dsum + 1e-10f);
  float4 r;
  r.x = acc.x * inv; r.y = acc.y * inv; r.z = acc.z * inv; r.w = acc.w * inv;
  *reinterpret_cast<float4*>(&out[(size_t)n * HDIM + tid * 4]) = r;
}

// ---------- layer-2 aggregation (bf16 msg, 2 edges in flight) ----------
__global__ __launch_bounds__(128) void agg2_kernel(
    const unsigned short* __restrict__ msg, const float* __restrict__ asrc,
    const float* __restrict__ adst, const float* __restrict__ maxv,
    const int* __restrict__ rowptr, const int* __restrict__ colsrc,
    float* __restrict__ out) {
  int n = blockIdx.x;
  int tid = threadIdx.x;
  int half = tid >> 6, ln = tid & 63;
  __shared__ int s_sh[64];
  __shared__ float coef_sh[64];
  __shared__ float red[129];
  float M = maxv[0];
  float ad = adst[n];
  int e0 = rowptr[n], e1 = rowptr[n + 1];
  float a0 = 0.f, a1 = 0.f, ds = 0.f;
  for (int base = e0; base < e1; base += 64) {
    int cnt = min(64, e1 - base);
    __syncthreads();
    if (tid < cnt) {
      int s = colsrc[base + tid];
      s_sh[tid] = s;
      float x = asrc[s] + ad;
      x = x >= 0.f ? x : 0.2f * x;
      coef_sh[tid] = __expf(x - M);
    }
    __syncthreads();
    for (int e = half; e < cnt; e += 2) {
      float c = coef_sh[e];
      ds += c;
      us2 m = *reinterpret_cast<const us2*>(&msg[(size_t)s_sh[e] * 128 + 2 * ln]);
      a0 = fmaf(bf2f(m[0]), c, a0);
      a1 = fmaf(bf2f(m[1]), c, a1);
    }
  }
  __syncthreads();
  if (half) {
    red[2 * ln] = a0; red[2 * ln + 1] = a1;
    if (ln == 0) red[128] = ds;
  }
  __syncthreads();
  if (!half) {
    float inv = 1.0f / (ds + red[128] + 1e-10f);
    float2 r;
    r.x = (a0 + red[2 * ln]) * inv;
    r.y = (a1 + red[2 * ln + 1]) * inv;
    *reinterpret_cast<float2*>(&out[(size_t)n * 128 + 2 * ln]) = r;
  }
}

// ---------- BN statistics ----------
__global__ void colstats_kernel(const float* __restrict__ X, float* __restrict__ sums,
                                float* __restrict__ sqs, int M, int C, int rowsPerBlock) {
  int c = blockIdx.x * blockDim.x + threadIdx.x;
  if (c >= C) return;
  int r0 = blockIdx.y * rowsPerBlock;
  int r1 = min(M, r0 + rowsPerBlock);
  float s = 0.f, s2 = 0.f;
  for (int r = r0; r < r1; ++r) {
    float v = X[(size_t)r * C + c];
    s += v; s2 = fmaf(v, v, s2);
  }
  atomicAdd(&sums[c], s);
  atomicAdd(&sqs[c], s2);
}

__global__ void bnparams_kernel(const float* __restrict__ sums, const float* __restrict__ sqs,
                                const float* __restrict__ gamma, const float* __restrict__ beta,
                                float* __restrict__ scale, float* __restrict__ shift,
                                int C, float invM) {
  int c = blockIdx.x * blockDim.x + threadIdx.x;
  if (c >= C) return;
  float mean = sums[c] * invM;
  float var = sqs[c] * invM - mean * mean;
  float inv = rsqrtf(var + 1e-5f);
  float sc = gamma[c] * inv;
  scale[c] = sc;
  shift[c] = beta[c] - mean * sc;
}

// ---------- fold layer-1 BN into W_out ----------
__global__ void foldw2_kernel(const float* __restrict__ W, const float* __restrict__ scale,
                              float* __restrict__ Wp) {
  int idx = blockIdx.x * 256 + threadIdx.x;
  if (idx >= HDIM * DIM_OUT) return;
  int c = idx >> 7;
  Wp[idx] = W[idx] * scale[c];
}

__global__ void bias2_kernel(const float* __restrict__ W, const float* __restrict__ shift,
                             float* __restrict__ bias2) {
  int j = threadIdx.x;
  if (j >= DIM_OUT) return;
  float s = 0.f;
  for (int c = 0; c < HDIM; ++c) s = fmaf(shift[c], W[c * DIM_OUT + j], s);
  bias2[j] = s;
}

// ---------- final: BN(out2) + residual ----------
__global__ void final_kernel(float* __restrict__ out, const float* __restrict__ resid,
                             const float* __restrict__ scale, const float* __restrict__ shift,
                             int total) {
  for (int i = blockIdx.x * blockDim.x + threadIdx.x; i < total; i += gridDim.x * blockDim.x) {
    int c = i & 127;
    out[i] = fmaf(out[i], scale[c], shift[c]) + resid[i];
  }
}

// ==================== host ====================
extern "C" void kernel_launch(void* const* d_in, const int* in_sizes, int n_in,
                              void* d_out, int out_size, void* d_ws, size_t ws_size,
                              hipStream_t stream) {
  const float* feat    = (const float*)d_in[0];
  const int*   edges   = (const int*)d_in[1];
  const int*   esrc    = edges;
  const int*   edst    = edges + N_EDGES;
  const float* W_heads = (const float*)d_in[2];
  const float* a_heads = (const float*)d_in[3];
  const float* gamma_h = (const float*)d_in[4];
  const float* beta_h  = (const float*)d_in[5];
  const float* W_out   = (const float*)d_in[6];
  const float* a_out   = (const float*)d_in[7];
  const float* gamma_o = (const float*)d_in[8];
  const float* beta_o  = (const float*)d_in[9];
  const float* W_res   = (const float*)d_in[10];
  const float* b_res   = (const float*)d_in[11];
  float* out = (float*)d_out;

  char* ws = (char*)d_ws;
  size_t off = 0;
  auto alloc = [&](size_t bytes) {
    void* p = ws + off;
    off = (off + bytes + 255) & ~(size_t)255;
    return p;
  };
  unsigned short* msg1 = (unsigned short*)alloc((size_t)N_NODES * HDIM * 2);  // bf16; reused as msg2
  float*    out1   = (float*)alloc((size_t)N_NODES * HDIM * 4);   // reused as resid
  float*    asrc1  = (float*)alloc((size_t)N_NODES * NHEADS * 4); // reused as asrc2
  float*    adst1  = (float*)alloc((size_t)N_NODES * NHEADS * 4); // reused as adst2
  int*      counts = (int*)alloc((size_t)N_NODES * 4);
  int*      cursor = (int*)alloc((size_t)N_NODES * 4);
  int*      rowptr = (int*)alloc((size_t)(N_NODES + 1) * 4);
  int*      colsrc = (int*)alloc((size_t)N_EDGES * 4);
  float*    part   = (float*)alloc((size_t)MAXBLK * 8 * 4);
  float*    maxv1  = (float*)alloc(8 * 4);
  float*    maxv2  = (float*)alloc(4);
  float*    colsum = (float*)alloc(HDIM * 4);
  float*    colsq  = (float*)alloc(HDIM * 4);
  float*    scale1 = (float*)alloc(HDIM * 4);
  float*    shift1 = (float*)alloc(HDIM * 4);
  float*    scale2 = (float*)alloc(DIM_OUT * 4);
  float*    shift2 = (float*)alloc(DIM_OUT * 4);
  float*    Wpack  = (float*)alloc((size_t)DIM_IN * HDIM * 4);
  float*    W2p    = (float*)alloc((size_t)HDIM * DIM_OUT * 4);
  float*    bias2  = (float*)alloc(DIM_OUT * 4);
  unsigned short* msg2 = msg1;
  float* resid = out1;
  float* asrc2 = asrc1; float* adst2 = adst1;
  (void)n_in; (void)in_sizes; (void)out_size; (void)ws_size;

  hipMemsetAsync(counts, 0, (size_t)N_NODES * 4, stream);
  hipMemsetAsync(cursor, 0, (size_t)N_NODES * 4, stream);
  hipMemsetAsync(colsum, 0, HDIM * 4, stream);
  hipMemsetAsync(colsq, 0, HDIM * 4, stream);

  // ---- layer 1 ----
  pack_w_heads<<<(DIM_IN * HDIM + 255) / 256, 256, 0, stream>>>(W_heads, Wpack);
  dim3 g1(HDIM / 128, (N_NODES + 127) / 128);
  gemm_bf<<<g1, 256, 0, stream>>>(feat, Wpack, msg1, nullptr, N_NODES, HDIM, DIM_IN);
  attn1_kernel<<<(N_NODES + 3) / 4, 256, 0, stream>>>(msg1, a_heads, asrc1, adst1, N_NODES);

  hist_kernel<<<2048, 256, 0, stream>>>(edst, counts, N_EDGES);
  scan_kernel<<<1, 1024, 0, stream>>>(counts, rowptr, N_NODES);
  scatter_kernel<<<2048, 256, 0, stream>>>(esrc, edst, rowptr, cursor, colsrc, N_EDGES);

  max1_part_kernel<<<MAXBLK, 256, 0, stream>>>(esrc, edst, asrc1, adst1, part, N_EDGES);
  max1_final_kernel<<<1, 64, 0, stream>>>(part, maxv1, MAXBLK);
  agg1_kernel<<<N_NODES, 128, 0, stream>>>(msg1, asrc1, adst1, maxv1, rowptr, colsrc, out1);

  colstats_kernel<<<dim3(HDIM / 128, 98), 128, 0, stream>>>(out1, colsum, colsq, N_NODES, HDIM, 512);
  bnparams_kernel<<<(HDIM + 127) / 128, 128, 0, stream>>>(colsum, colsq, gamma_h, beta_h,
                                                          scale1, shift1, HDIM, 1.0f / N_NODES);
  foldw2_kernel<<<(HDIM * DIM_OUT + 255) / 256, 256, 0, stream>>>(W_out, scale1, W2p);
  bias2_kernel<<<1, 128, 0, stream>>>(W_out, shift1, bias2);

  // ---- layer 2 ----
  dim3 g2(DIM_OUT / 128, (N_NODES + 127) / 128);
  gemm_bf<<<g2, 256, 0, stream>>>(out1, W2p, msg2, bias2, N_NODES, DIM_OUT, HDIM);
  attn2_kernel<<<(N_NODES + 3) / 4, 256, 0, stream>>>(msg2, a_out, asrc2, adst2, N_NODES);

  max2_part_kernel<<<MAXBLK, 256, 0, stream>>>(esrc, edst, asrc2, adst2, part, N_EDGES);
  max2_final_kernel<<<1, 64, 0, stream>>>(part, maxv2, MAXBLK);
  agg2_kernel<<<N_NODES, 128, 0, stream>>>(msg2, asrc2, adst2, maxv2, rowptr, colsrc, out);

  // residual GEMM (out1 dead after gemm2)
  gemm_f32<<<g2, 256, 0, stream>>>(feat, W_res, resid, b_res, N_NODES, DIM_OUT, DIM_IN);

  // layer-2 BN + residual
  hipMemsetAsync(colsum, 0, HDIM * 4, stream);
  hipMemsetAsync(colsq, 0, HDIM * 4, stream);
  colstats_kernel<<<dim3(1, 98), 128, 0, stream>>>(out, colsum, colsq, N_NODES, DIM_OUT, 512);
  bnparams_kernel<<<1, 128, 0, stream>>>(colsum, colsq, gamma_o, beta_o,
                                         scale2, shift2, DIM_OUT, 1.0f / N_NODES);
  final_kernel<<<2048, 256, 0, stream>>>(out, resid, scale2, shift2, N_NODES * DIM_OUT);
}

// Round 4
// 1024.296 us; speedup vs baseline: 3.0619x; 1.1584x over previous
//
#include <hip/hip_runtime.h>
#include <math.h>

#define N_NODES 50000
#define N_EDGES 1600000
#define DIM_IN  128
#define DIM_HID 64
#define NHEADS  8
#define HDIM    (NHEADS*DIM_HID)   // 512
#define DIM_OUT 128
#define MAXBLK  512
#define LDK     72                 // padded LDS row (bf16 elems): 144B = 9*16B

typedef __attribute__((ext_vector_type(2))) unsigned short us2;
typedef __attribute__((ext_vector_type(4))) unsigned short us4;
typedef __attribute__((ext_vector_type(8))) unsigned short us8;
typedef __attribute__((ext_vector_type(8))) short bf16x8;   // 8 bf16 (4 VGPRs)
typedef __attribute__((ext_vector_type(4))) float f32x4;

__device__ __forceinline__ float leaky(float x) { return x >= 0.f ? x : 0.2f * x; }
__device__ __forceinline__ float bf2f(unsigned short h) {
  return __uint_as_float(((unsigned)h) << 16);
}
__device__ __forceinline__ unsigned short f2bf(float f) {
  unsigned u = __float_as_uint(f);
  unsigned r = (u + 0x7fffu + ((u >> 16) & 1u)) >> 16;
  return (unsigned short)r;
}

// ---------- fp32 -> bf16 convert (vectorized) ----------
__global__ void cvt_f2bf_kernel(const float* __restrict__ X, unsigned short* __restrict__ Y, int n4) {
  int i = blockIdx.x * 256 + threadIdx.x;
  if (i >= n4) return;
  float4 v = *reinterpret_cast<const float4*>(&X[(size_t)i * 4]);
  us4 o;
  o[0] = f2bf(v.x); o[1] = f2bf(v.y); o[2] = f2bf(v.z); o[3] = f2bf(v.w);
  *reinterpret_cast<us4*>(&Y[(size_t)i * 4]) = o;
}

// ---------- pack W_heads [8][128][64] -> Bt1 [512][128] bf16 (n-major, k-minor) ----------
__global__ void packw1_kernel(const float* __restrict__ Wh, unsigned short* __restrict__ Bt) {
  int idx = blockIdx.x * 256 + threadIdx.x;
  if (idx >= HDIM * DIM_IN) return;
  int n = idx >> 7, k = idx & 127;
  Bt[idx] = f2bf(Wh[(n >> 6) * (DIM_IN * DIM_HID) + k * DIM_HID + (n & 63)]);
}

// ---------- fold BN1 scale into W_out -> Bt2 [128][512] bf16 ----------
__global__ void foldw2_kernel(const float* __restrict__ W, const float* __restrict__ scale,
                              unsigned short* __restrict__ Bt) {
  int idx = blockIdx.x * 256 + threadIdx.x;
  if (idx >= DIM_OUT * HDIM) return;
  int n = idx >> 9, k = idx & 511;
  Bt[idx] = f2bf(W[k * DIM_OUT + n] * scale[k]);
}

// ---------- pack W_res [128][128] -> Btr [128][128] bf16 (transposed) ----------
__global__ void packwres_kernel(const float* __restrict__ W, unsigned short* __restrict__ Bt) {
  int idx = blockIdx.x * 256 + threadIdx.x;
  if (idx >= DIM_OUT * DIM_IN) return;
  int n = idx >> 7, k = idx & 127;
  Bt[idx] = f2bf(W[k * DIM_OUT + n]);
}

// ---------- bf16 MFMA GEMM: C[M,N] = A[M,K] @ Bt[N,K]^T (+bias) ----------
// 128x128 tile, 4 waves (64x64 each), BK=64, 16x16x32 bf16 MFMA, fp32 acc.
template<int OUTBF>
__global__ __launch_bounds__(256) void gemm_mfma(
    const unsigned short* __restrict__ A, const unsigned short* __restrict__ Bt,
    void* __restrict__ Cout, const float* __restrict__ bias,
    int M, int N, int K) {
  __shared__ unsigned short As[128 * LDK];
  __shared__ unsigned short Bs[128 * LDK];
  const int tid = threadIdx.x;
  const int lane = tid & 63, wid = tid >> 6;
  const int wr = wid >> 1, wc = wid & 1;
  const int l15 = lane & 15, lhi = lane >> 4;
  const int m0 = blockIdx.y * 128, n0 = blockIdx.x * 128;
  const int srow = tid >> 3;              // 0..31 per pass
  const int sc8 = (tid - srow) & 7;       // swizzled 16B chunk (even bank spread)
  f32x4 acc[4][4];
#pragma unroll
  for (int i = 0; i < 4; ++i)
#pragma unroll
    for (int j = 0; j < 4; ++j) acc[i][j] = f32x4{0.f, 0.f, 0.f, 0.f};

  for (int k0 = 0; k0 < K; k0 += 64) {
    __syncthreads();
#pragma unroll
    for (int p = 0; p < 4; ++p) {
      int row = p * 32 + srow;
      us8 va = {0, 0, 0, 0, 0, 0, 0, 0};
      int gr = m0 + row;
      if (gr < M) va = *reinterpret_cast<const us8*>(&A[(size_t)gr * K + k0 + sc8 * 8]);
      *reinterpret_cast<us8*>(&As[row * LDK + sc8 * 8]) = va;
      us8 vb = {0, 0, 0, 0, 0, 0, 0, 0};
      int gn = n0 + row;
      if (gn < N) vb = *reinterpret_cast<const us8*>(&Bt[(size_t)gn * K + k0 + sc8 * 8]);
      *reinterpret_cast<us8*>(&Bs[row * LDK + sc8 * 8]) = vb;
    }
    __syncthreads();
#pragma unroll
    for (int kk = 0; kk < 2; ++kk) {
      bf16x8 af[4], bfr[4];
#pragma unroll
      for (int i = 0; i < 4; ++i)
        af[i] = *reinterpret_cast<const bf16x8*>(&As[(wr * 64 + i * 16 + l15) * LDK + kk * 32 + lhi * 8]);
#pragma unroll
      for (int j = 0; j < 4; ++j)
        bfr[j] = *reinterpret_cast<const bf16x8*>(&Bs[(wc * 64 + j * 16 + l15) * LDK + kk * 32 + lhi * 8]);
#pragma unroll
      for (int i = 0; i < 4; ++i)
#pragma unroll
        for (int j = 0; j < 4; ++j)
          acc[i][j] = __builtin_amdgcn_mfma_f32_16x16x32_bf16(af[i], bfr[j], acc[i][j], 0, 0, 0);
    }
  }
#pragma unroll
  for (int j = 0; j < 4; ++j) {
    int col = n0 + wc * 64 + j * 16 + l15;
    float bb = bias ? bias[col] : 0.f;
#pragma unroll
    for (int i = 0; i < 4; ++i) {
      f32x4 v = acc[i][j];
#pragma unroll
      for (int t = 0; t < 4; ++t) {
        int row = m0 + wr * 64 + i * 16 + lhi * 4 + t;
        if (row < M) {
          float o = v[t] + bb;
          if (OUTBF) ((unsigned short*)Cout)[(size_t)row * N + col] = f2bf(o);
          else       ((float*)Cout)[(size_t)row * N + col] = o;
        }
      }
    }
  }
}

// ---------- attn projections layer 1 (bf16 msg) ----------
__global__ __launch_bounds__(256) void attn1_kernel(
    const unsigned short* __restrict__ msg, const float* __restrict__ a_heads,
    float* __restrict__ asrc, float* __restrict__ adst, int Nn) {
  int lane = threadIdx.x & 63;
  int n = blockIdx.x * 4 + (threadIdx.x >> 6);
  if (n >= Nn) return;
  us8 v = *reinterpret_cast<const us8*>(&msg[(size_t)n * HDIM + lane * 8]);
  int h = lane >> 3, p0 = (lane & 7) * 8;
  float s = 0.f, d = 0.f;
#pragma unroll
  for (int j = 0; j < 8; ++j) {
    float f = bf2f(v[j]);
    s = fmaf(f, a_heads[h * 128 + p0 + j], s);
    d = fmaf(f, a_heads[h * 128 + 64 + p0 + j], d);
  }
  s += __shfl_xor(s, 1, 64); s += __shfl_xor(s, 2, 64); s += __shfl_xor(s, 4, 64);
  d += __shfl_xor(d, 1, 64); d += __shfl_xor(d, 2, 64); d += __shfl_xor(d, 4, 64);
  if ((lane & 7) == 0) { asrc[n * 8 + h] = s; adst[n * 8 + h] = d; }
}

// ---------- attn projections layer 2 (bf16 msg) ----------
__global__ __launch_bounds__(256) void attn2_kernel(
    const unsigned short* __restrict__ msg, const float* __restrict__ a_out,
    float* __restrict__ asrc, float* __restrict__ adst, int Nn) {
  int lane = threadIdx.x & 63;
  int n = blockIdx.x * 4 + (threadIdx.x >> 6);
  if (n >= Nn) return;
  us2 v = *reinterpret_cast<const us2*>(&msg[(size_t)n * 128 + lane * 2]);
  float f0 = bf2f(v[0]), f1 = bf2f(v[1]);
  float s = f0 * a_out[2 * lane] + f1 * a_out[2 * lane + 1];
  float d = f0 * a_out[128 + 2 * lane] + f1 * a_out[128 + 2 * lane + 1];
#pragma unroll
  for (int off = 32; off; off >>= 1) {
    s += __shfl_xor(s, off, 64);
    d += __shfl_xor(d, off, 64);
  }
  if (lane == 0) { asrc[n] = s; adst[n] = d; }
}

// ---------- CSR build ----------
__global__ void hist_kernel(const int* __restrict__ edst, int* __restrict__ counts, int E) {
  for (int e = blockIdx.x * blockDim.x + threadIdx.x; e < E; e += gridDim.x * blockDim.x)
    atomicAdd(&counts[edst[e]], 1);
}

__global__ __launch_bounds__(1024) void scan_kernel(
    const int* __restrict__ counts, int* __restrict__ rowptr, int n) {
  __shared__ int tmp[1024];
  __shared__ int carry_sh;
  int tid = threadIdx.x;
  if (tid == 0) carry_sh = 0;
  __syncthreads();
  for (int base = 0; base < n; base += 1024) {
    int i = base + tid;
    int v = (i < n) ? counts[i] : 0;
    tmp[tid] = v;
    __syncthreads();
    int x = v;
    for (int off = 1; off < 1024; off <<= 1) {
      int t = (tid >= off) ? tmp[tid - off] : 0;
      __syncthreads();
      x += t;
      tmp[tid] = x;
      __syncthreads();
    }
    int carry = carry_sh;
    if (i < n) rowptr[i] = carry + x - v;
    int total = tmp[1023];
    __syncthreads();
    if (tid == 0) carry_sh = carry + total;
    __syncthreads();
  }
  if (tid == 0) rowptr[n] = carry_sh;
}

__global__ void scatter_kernel(const int* __restrict__ esrc, const int* __restrict__ edst,
                               const int* __restrict__ rowptr, int* __restrict__ cursor,
                               int* __restrict__ colsrc, int E) {
  for (int e = blockIdx.x * blockDim.x + threadIdx.x; e < E; e += gridDim.x * blockDim.x) {
    int d = edst[e];
    int pos = rowptr[d] + atomicAdd(&cursor[d], 1);
    colsrc[pos] = esrc[e];
  }
}

// ---------- layer-1 max, two-stage ----------
__global__ __launch_bounds__(256) void max1_part_kernel(
    const int* __restrict__ esrc, const int* __restrict__ edst,
    const float* __restrict__ asrc, const float* __restrict__ adst,
    float* __restrict__ part, int E) {
  float m[8];
#pragma unroll
  for (int h = 0; h < 8; ++h) m[h] = -3.4e38f;
  for (int e = blockIdx.x * blockDim.x + threadIdx.x; e < E; e += gridDim.x * blockDim.x) {
    int s = esrc[e], d = edst[e];
    float4 s0 = *reinterpret_cast<const float4*>(&asrc[(size_t)s * 8]);
    float4 s1 = *reinterpret_cast<const float4*>(&asrc[(size_t)s * 8 + 4]);
    float4 d0 = *reinterpret_cast<const float4*>(&adst[(size_t)d * 8]);
    float4 d1 = *reinterpret_cast<const float4*>(&adst[(size_t)d * 8 + 4]);
    float xs[8] = {s0.x + d0.x, s0.y + d0.y, s0.z + d0.z, s0.w + d0.w,
                   s1.x + d1.x, s1.y + d1.y, s1.z + d1.z, s1.w + d1.w};
#pragma unroll
    for (int h = 0; h < 8; ++h) m[h] = fmaxf(m[h], leaky(xs[h]));
  }
#pragma unroll
  for (int h = 0; h < 8; ++h)
#pragma unroll
    for (int off = 32; off; off >>= 1) m[h] = fmaxf(m[h], __shfl_xor(m[h], off, 64));
  __shared__ float sm[4][8];
  int wv = threadIdx.x >> 6, ln = threadIdx.x & 63;
  if (ln == 0)
#pragma unroll
    for (int h = 0; h < 8; ++h) sm[wv][h] = m[h];
  __syncthreads();
  if (threadIdx.x < 8) {
    int h = threadIdx.x;
    part[blockIdx.x * 8 + h] =
        fmaxf(fmaxf(sm[0][h], sm[1][h]), fmaxf(sm[2][h], sm[3][h]));
  }
}

__global__ void max1_final_kernel(const float* __restrict__ part, float* __restrict__ maxv, int nblk) {
  int t = threadIdx.x;
  int h = t & 7, k = t >> 3;
  float m = -3.4e38f;
  for (int i = k; i < nblk; i += 8) m = fmaxf(m, part[i * 8 + h]);
  m = fmaxf(m, __shfl_xor(m, 8, 64));
  m = fmaxf(m, __shfl_xor(m, 16, 64));
  m = fmaxf(m, __shfl_xor(m, 32, 64));
  if (t < 8) maxv[t] = m;
}

// ---------- layer-2 max, two-stage ----------
__global__ __launch_bounds__(256) void max2_part_kernel(
    const int* __restrict__ esrc, const int* __restrict__ edst,
    const float* __restrict__ asrc, const float* __restrict__ adst,
    float* __restrict__ part, int E) {
  float m = -3.4e38f;
  for (int e = blockIdx.x * blockDim.x + threadIdx.x; e < E; e += gridDim.x * blockDim.x) {
    float x = asrc[esrc[e]] + adst[edst[e]];
    m = fmaxf(m, leaky(x));
  }
#pragma unroll
  for (int off = 32; off; off >>= 1) m = fmaxf(m, __shfl_xor(m, off, 64));
  __shared__ float sm[4];
  int wv = threadIdx.x >> 6, ln = threadIdx.x & 63;
  if (ln == 0) sm[wv] = m;
  __syncthreads();
  if (threadIdx.x == 0)
    part[blockIdx.x] = fmaxf(fmaxf(sm[0], sm[1]), fmaxf(sm[2], sm[3]));
}

__global__ void max2_final_kernel(const float* __restrict__ part, float* __restrict__ maxv, int nblk) {
  int t = threadIdx.x;
  float m = -3.4e38f;
  for (int i = t; i < nblk; i += 64) m = fmaxf(m, part[i]);
#pragma unroll
  for (int off = 32; off; off >>= 1) m = fmaxf(m, __shfl_xor(m, off, 64));
  if (t == 0) maxv[0] = m;
}

// ---------- layer-1 aggregation (bf16 msg in, bf16 out, fused denom, unroll 2) ----------
__global__ __launch_bounds__(128) void agg1_kernel(
    const unsigned short* __restrict__ msg, const float* __restrict__ asrc,
    const float* __restrict__ adst, const float* __restrict__ maxv,
    const int* __restrict__ rowptr, const int* __restrict__ colsrc,
    unsigned short* __restrict__ out) {
  int n = blockIdx.x;
  int tid = threadIdx.x;
  __shared__ int s_sh[64];
  __shared__ float coef_sh[64][8];
  __shared__ float hdr[16];
  if (tid < 8) {
    hdr[tid] = maxv[tid];
    hdr[8 + tid] = adst[(size_t)n * 8 + tid];
  }
  __syncthreads();
  const int h = tid >> 4;
  const int e0 = rowptr[n], e1 = rowptr[n + 1];
  float4 acc = make_float4(0.f, 0.f, 0.f, 0.f);
  float dsum = 0.f;
  for (int base = e0; base < e1; base += 64) {
    int cnt = min(64, e1 - base);
    __syncthreads();
#pragma unroll
    for (int q = 0; q < 4; ++q) {
      int slot = q * 128 + tid;
      int el = slot >> 3, hh = slot & 7;
      if (el < cnt) {
        int s = colsrc[base + el];
        if (hh == 0) s_sh[el] = s;
        float x = asrc[(size_t)s * 8 + hh] + hdr[8 + hh];
        x = x >= 0.f ? x : 0.2f * x;
        coef_sh[el][hh] = __expf(x - hdr[hh]);
      }
    }
    __syncthreads();
    int e = 0;
    for (; e + 2 <= cnt; e += 2) {
      int sA = s_sh[e], sB = s_sh[e + 1];
      us4 ma = *reinterpret_cast<const us4*>(&msg[(size_t)sA * HDIM + tid * 4]);
      us4 mb = *reinterpret_cast<const us4*>(&msg[(size_t)sB * HDIM + tid * 4]);
      float ca = coef_sh[e][h], cb = coef_sh[e + 1][h];
      dsum += ca + cb;
      acc.x = fmaf(bf2f(ma[0]), ca, acc.x);
      acc.y = fmaf(bf2f(ma[1]), ca, acc.y);
      acc.z = fmaf(bf2f(ma[2]), ca, acc.z);
      acc.w = fmaf(bf2f(ma[3]), ca, acc.w);
      acc.x = fmaf(bf2f(mb[0]), cb, acc.x);
      acc.y = fmaf(bf2f(mb[1]), cb, acc.y);
      acc.z = fmaf(bf2f(mb[2]), cb, acc.z);
      acc.w = fmaf(bf2f(mb[3]), cb, acc.w);
    }
    if (e < cnt) {
      int s = s_sh[e];
      float c = coef_sh[e][h];
      dsum += c;
      us4 m4 = *reinterpret_cast<const us4*>(&msg[(size_t)s * HDIM + tid * 4]);
      acc.x = fmaf(bf2f(m4[0]), c, acc.x);
      acc.y = fmaf(bf2f(m4[1]), c, acc.y);
      acc.z = fmaf(bf2f(m4[2]), c, acc.z);
      acc.w = fmaf(bf2f(m4[3]), c, acc.w);
    }
  }
  float inv = 1.0f / (dsum + 1e-10f);
  us4 o;
  o[0] = f2bf(acc.x * inv); o[1] = f2bf(acc.y * inv);
  o[2] = f2bf(acc.z * inv); o[3] = f2bf(acc.w * inv);
  *reinterpret_cast<us4*>(&out[(size_t)n * HDIM + tid * 4]) = o;
}

// ---------- layer-2 aggregation (bf16 msg, fp32 out, unroll 2) ----------
__global__ __launch_bounds__(128) void agg2_kernel(
    const unsigned short* __restrict__ msg, const float* __restrict__ asrc,
    const float* __restrict__ adst, const float* __restrict__ maxv,
    const int* __restrict__ rowptr, const int* __restrict__ colsrc,
    float* __restrict__ out) {
  int n = blockIdx.x;
  int tid = threadIdx.x;
  int half = tid >> 6, ln = tid & 63;
  __shared__ int s_sh[64];
  __shared__ float coef_sh[64];
  __shared__ float red[129];
  float M = maxv[0];
  float ad = adst[n];
  int e0 = rowptr[n], e1 = rowptr[n + 1];
  float a0 = 0.f, a1 = 0.f, ds = 0.f;
  for (int base = e0; base < e1; base += 64) {
    int cnt = min(64, e1 - base);
    __syncthreads();
    if (tid < cnt) {
      int s = colsrc[base + tid];
      s_sh[tid] = s;
      float x = asrc[s] + ad;
      x = x >= 0.f ? x : 0.2f * x;
      coef_sh[tid] = __expf(x - M);
    }
    __syncthreads();
    int e = half;
    for (; e + 2 < cnt; e += 4) {
      int sA = s_sh[e], sB = s_sh[e + 2];
      us2 ma = *reinterpret_cast<const us2*>(&msg[(size_t)sA * 128 + 2 * ln]);
      us2 mb = *reinterpret_cast<const us2*>(&msg[(size_t)sB * 128 + 2 * ln]);
      float ca = coef_sh[e], cb = coef_sh[e + 2];
      ds += ca + cb;
      a0 = fmaf(bf2f(ma[0]), ca, a0);
      a1 = fmaf(bf2f(ma[1]), ca, a1);
      a0 = fmaf(bf2f(mb[0]), cb, a0);
      a1 = fmaf(bf2f(mb[1]), cb, a1);
    }
    for (; e < cnt; e += 2) {
      float c = coef_sh[e];
      ds += c;
      us2 m = *reinterpret_cast<const us2*>(&msg[(size_t)s_sh[e] * 128 + 2 * ln]);
      a0 = fmaf(bf2f(m[0]), c, a0);
      a1 = fmaf(bf2f(m[1]), c, a1);
    }
  }
  __syncthreads();
  if (half) {
    red[2 * ln] = a0; red[2 * ln + 1] = a1;
    if (ln == 0) red[128] = ds;
  }
  __syncthreads();
  if (!half) {
    float inv = 1.0f / (ds + red[128] + 1e-10f);
    float2 r;
    r.x = (a0 + red[2 * ln]) * inv;
    r.y = (a1 + red[2 * ln + 1]) * inv;
    *reinterpret_cast<float2*>(&out[(size_t)n * 128 + 2 * ln]) = r;
  }
}

// ---------- BN statistics (fp32 input) ----------
__global__ void colstats_kernel(const float* __restrict__ X, float* __restrict__ sums,
                                float* __restrict__ sqs, int M, int C, int rowsPerBlock) {
  int c = blockIdx.x * blockDim.x + threadIdx.x;
  if (c >= C) return;
  int r0 = blockIdx.y * rowsPerBlock;
  int r1 = min(M, r0 + rowsPerBlock);
  float s = 0.f, s2 = 0.f;
  for (int r = r0; r < r1; ++r) {
    float v = X[(size_t)r * C + c];
    s += v; s2 = fmaf(v, v, s2);
  }
  atomicAdd(&sums[c], s);
  atomicAdd(&sqs[c], s2);
}

// ---------- BN statistics (bf16 input) ----------
__global__ void colstats_bf_kernel(const unsigned short* __restrict__ X, float* __restrict__ sums,
                                   float* __restrict__ sqs, int M, int C, int rowsPerBlock) {
  int c = blockIdx.x * blockDim.x + threadIdx.x;
  if (c >= C) return;
  int r0 = blockIdx.y * rowsPerBlock;
  int r1 = min(M, r0 + rowsPerBlock);
  float s = 0.f, s2 = 0.f;
  for (int r = r0; r < r1; ++r) {
    float v = bf2f(X[(size_t)r * C + c]);
    s += v; s2 = fmaf(v, v, s2);
  }
  atomicAdd(&sums[c], s);
  atomicAdd(&sqs[c], s2);
}

__global__ void bnparams_kernel(const float* __restrict__ sums, const float* __restrict__ sqs,
                                const float* __restrict__ gamma, const float* __restrict__ beta,
                                float* __restrict__ scale, float* __restrict__ shift,
                                int C, float invM) {
  int c = blockIdx.x * blockDim.x + threadIdx.x;
  if (c >= C) return;
  float mean = sums[c] * invM;
  float var = sqs[c] * invM - mean * mean;
  float inv = rsqrtf(var + 1e-5f);
  float sc = gamma[c] * inv;
  scale[c] = sc;
  shift[c] = beta[c] - mean * sc;
}

__global__ void bias2_kernel(const float* __restrict__ W, const float* __restrict__ shift,
                             float* __restrict__ bias2) {
  int j = threadIdx.x;
  if (j >= DIM_OUT) return;
  float s = 0.f;
  for (int c = 0; c < HDIM; ++c) s = fmaf(shift[c], W[c * DIM_OUT + j], s);
  bias2[j] = s;
}

// ---------- final: BN(out2) + residual ----------
__global__ void final_kernel(float* __restrict__ out, const float* __restrict__ resid,
                             const float* __restrict__ scale, const float* __restrict__ shift,
                             int total) {
  for (int i = blockIdx.x * blockDim.x + threadIdx.x; i < total; i += gridDim.x * blockDim.x) {
    int c = i & 127;
    out[i] = fmaf(out[i], scale[c], shift[c]) + resid[i];
  }
}

// ==================== host ====================
extern "C" void kernel_launch(void* const* d_in, const int* in_sizes, int n_in,
                              void* d_out, int out_size, void* d_ws, size_t ws_size,
                              hipStream_t stream) {
  const float* feat    = (const float*)d_in[0];
  const int*   edges   = (const int*)d_in[1];
  const int*   esrc    = edges;
  const int*   edst    = edges + N_EDGES;
  const float* W_heads = (const float*)d_in[2];
  const float* a_heads = (const float*)d_in[3];
  const float* gamma_h = (const float*)d_in[4];
  const float* beta_h  = (const float*)d_in[5];
  const float* W_out   = (const float*)d_in[6];
  const float* a_out   = (const float*)d_in[7];
  const float* gamma_o = (const float*)d_in[8];
  const float* beta_o  = (const float*)d_in[9];
  const float* W_res   = (const float*)d_in[10];
  const float* b_res   = (const float*)d_in[11];
  float* out = (float*)d_out;

  char* ws = (char*)d_ws;
  size_t off = 0;
  auto alloc = [&](size_t bytes) {
    void* p = ws + off;
    off = (off + bytes + 255) & ~(size_t)255;
    return p;
  };
  unsigned short* msg1    = (unsigned short*)alloc((size_t)N_NODES * HDIM * 2);  // reused as msg2
  unsigned short* out1_bf = (unsigned short*)alloc((size_t)N_NODES * HDIM * 2);
  unsigned short* feat_bf = (unsigned short*)alloc((size_t)N_NODES * DIM_IN * 2);
  float*    resid  = (float*)alloc((size_t)N_NODES * DIM_OUT * 4);
  float*    asrc1  = (float*)alloc((size_t)N_NODES * NHEADS * 4); // reused as asrc2
  float*    adst1  = (float*)alloc((size_t)N_NODES * NHEADS * 4); // reused as adst2
  int*      counts = (int*)alloc((size_t)N_NODES * 4);
  int*      cursor = (int*)alloc((size_t)N_NODES * 4);
  int*      rowptr = (int*)alloc((size_t)(N_NODES + 1) * 4);
  int*      colsrc = (int*)alloc((size_t)N_EDGES * 4);
  float*    part   = (float*)alloc((size_t)MAXBLK * 8 * 4);
  float*    maxv1  = (float*)alloc(8 * 4);
  float*    maxv2  = (float*)alloc(4);
  float*    colsum = (float*)alloc(HDIM * 4);
  float*    colsq  = (float*)alloc(HDIM * 4);
  float*    scale1 = (float*)alloc(HDIM * 4);
  float*    shift1 = (float*)alloc(HDIM * 4);
  float*    scale2 = (float*)alloc(DIM_OUT * 4);
  float*    shift2 = (float*)alloc(DIM_OUT * 4);
  unsigned short* Bt1 = (unsigned short*)alloc((size_t)HDIM * DIM_IN * 2);
  unsigned short* Bt2 = (unsigned short*)alloc((size_t)DIM_OUT * HDIM * 2);
  unsigned short* Btr = (unsigned short*)alloc((size_t)DIM_OUT * DIM_IN * 2);
  float*    bias2  = (float*)alloc(DIM_OUT * 4);
  unsigned short* msg2 = msg1;
  float* asrc2 = asrc1; float* adst2 = adst1;
  (void)n_in; (void)in_sizes; (void)out_size; (void)ws_size;

  hipMemsetAsync(counts, 0, (size_t)N_NODES * 4, stream);
  hipMemsetAsync(cursor, 0, (size_t)N_NODES * 4, stream);
  hipMemsetAsync(colsum, 0, HDIM * 4, stream);
  hipMemsetAsync(colsq, 0, HDIM * 4, stream);

  // ---- packs / converts ----
  cvt_f2bf_kernel<<<(N_NODES * DIM_IN / 4 + 255) / 256, 256, 0, stream>>>(feat, feat_bf, N_NODES * DIM_IN / 4);
  packw1_kernel<<<(HDIM * DIM_IN + 255) / 256, 256, 0, stream>>>(W_heads, Bt1);
  packwres_kernel<<<(DIM_OUT * DIM_IN + 255) / 256, 256, 0, stream>>>(W_res, Btr);

  // ---- layer 1 ----
  dim3 g1(HDIM / 128, (N_NODES + 127) / 128);
  gemm_mfma<1><<<g1, 256, 0, stream>>>(feat_bf, Bt1, msg1, nullptr, N_NODES, HDIM, DIM_IN);
  attn1_kernel<<<(N_NODES + 3) / 4, 256, 0, stream>>>(msg1, a_heads, asrc1, adst1, N_NODES);

  hist_kernel<<<2048, 256, 0, stream>>>(edst, counts, N_EDGES);
  scan_kernel<<<1, 1024, 0, stream>>>(counts, rowptr, N_NODES);
  scatter_kernel<<<2048, 256, 0, stream>>>(esrc, edst, rowptr, cursor, colsrc, N_EDGES);

  max1_part_kernel<<<MAXBLK, 256, 0, stream>>>(esrc, edst, asrc1, adst1, part, N_EDGES);
  max1_final_kernel<<<1, 64, 0, stream>>>(part, maxv1, MAXBLK);
  agg1_kernel<<<N_NODES, 128, 0, stream>>>(msg1, asrc1, adst1, maxv1, rowptr, colsrc, out1_bf);

  colstats_bf_kernel<<<dim3(HDIM / 128, 98), 128, 0, stream>>>(out1_bf, colsum, colsq, N_NODES, HDIM, 512);
  bnparams_kernel<<<(HDIM + 127) / 128, 128, 0, stream>>>(colsum, colsq, gamma_h, beta_h,
                                                          scale1, shift1, HDIM, 1.0f / N_NODES);
  foldw2_kernel<<<(DIM_OUT * HDIM + 255) / 256, 256, 0, stream>>>(W_out, scale1, Bt2);
  bias2_kernel<<<1, 128, 0, stream>>>(W_out, shift1, bias2);

  // ---- layer 2 ----
  dim3 g2(DIM_OUT / 128, (N_NODES + 127) / 128);
  gemm_mfma<1><<<g2, 256, 0, stream>>>(out1_bf, Bt2, msg2, bias2, N_NODES, DIM_OUT, HDIM);
  attn2_kernel<<<(N_NODES + 3) / 4, 256, 0, stream>>>(msg2, a_out, asrc2, adst2, N_NODES);

  max2_part_kernel<<<MAXBLK, 256, 0, stream>>>(esrc, edst, asrc2, adst2, part, N_EDGES);
  max2_final_kernel<<<1, 64, 0, stream>>>(part, maxv2, MAXBLK);
  agg2_kernel<<<N_NODES, 128, 0, stream>>>(msg2, asrc2, adst2, maxv2, rowptr, colsrc, out);

  // residual GEMM (bf16 MFMA, fp32 out)
  gemm_mfma<0><<<g2, 256, 0, stream>>>(feat_bf, Btr, resid, b_res, N_NODES, DIM_OUT, DIM_IN);

  // layer-2 BN + residual
  hipMemsetAsync(colsum, 0, HDIM * 4, stream);
  hipMemsetAsync(colsq, 0, HDIM * 4, stream);
  colstats_kernel<<<dim3(1, 98), 128, 0, stream>>>(out, colsum, colsq, N_NODES, DIM_OUT, 512);
  bnparams_kernel<<<1, 128, 0, stream>>>(colsum, colsq, gamma_o, beta_o,
                                         scale2, shift2, DIM_OUT, 1.0f / N_NODES);
  final_kernel<<<2048, 256, 0, stream>>>(out, resid, scale2, shift2, N_NODES * DIM_OUT);
}

// Round 5
// 917.382 us; speedup vs baseline: 3.4187x; 1.1165x over previous
//
#include <hip/hip_runtime.h>
#include <math.h>

#define N_NODES 50000
#define N_EDGES 1600000
#define DIM_IN  128
#define DIM_HID 64
#define NHEADS  8
#define HDIM    (NHEADS*DIM_HID)   // 512
#define DIM_OUT 128
#define SMBLK   1024               // blocks for scatter+max1 pass
#define MAXBLK  512                // blocks for max2 pass
#define LDK     72                 // padded LDS row (bf16 elems)

typedef __attribute__((ext_vector_type(2))) unsigned short us2;
typedef __attribute__((ext_vector_type(4))) unsigned short us4;
typedef __attribute__((ext_vector_type(8))) unsigned short us8;
typedef __attribute__((ext_vector_type(8))) short bf16x8;
typedef __attribute__((ext_vector_type(4))) float f32x4;

__device__ __forceinline__ float leaky(float x) { return x >= 0.f ? x : 0.2f * x; }
__device__ __forceinline__ float bf2f(unsigned short h) {
  return __uint_as_float(((unsigned)h) << 16);
}
__device__ __forceinline__ unsigned short f2bf(float f) {
  unsigned u = __float_as_uint(f);
  unsigned r = (u + 0x7fffu + ((u >> 16) & 1u)) >> 16;
  return (unsigned short)r;
}

// ---------- fused prep: cvt feat->bf16 | pack W_heads | pack W_res ----------
// blocks [0,6250): cvt, [6250,6506): packw1, [6506,6570): packwres
__global__ void prep_kernel(const float* __restrict__ feat, const float* __restrict__ Wh,
                            const float* __restrict__ Wres,
                            unsigned short* __restrict__ feat_bf,
                            unsigned short* __restrict__ Bt1,
                            unsigned short* __restrict__ Btr) {
  int b = blockIdx.x;
  if (b < 6250) {
    int i = b * 256 + threadIdx.x;          // i < 1.6M quads
    float4 v = *reinterpret_cast<const float4*>(&feat[(size_t)i * 4]);
    us4 o;
    o[0] = f2bf(v.x); o[1] = f2bf(v.y); o[2] = f2bf(v.z); o[3] = f2bf(v.w);
    *reinterpret_cast<us4*>(&feat_bf[(size_t)i * 4]) = o;
  } else if (b < 6506) {
    int idx = (b - 6250) * 256 + threadIdx.x;  // < 512*128
    int n = idx >> 7, k = idx & 127;
    Bt1[idx] = f2bf(Wh[(n >> 6) * (DIM_IN * DIM_HID) + k * DIM_HID + (n & 63)]);
  } else {
    int idx = (b - 6506) * 256 + threadIdx.x;  // < 128*128
    int n = idx >> 7, k = idx & 127;
    Btr[idx] = f2bf(Wres[k * DIM_OUT + n]);
  }
}

// ---------- fold BN1 scale into W_out -> Bt2 [128][512] bf16 ----------
__global__ void foldw2_kernel(const float* __restrict__ W, const float* __restrict__ scale,
                              unsigned short* __restrict__ Bt) {
  int idx = blockIdx.x * 256 + threadIdx.x;
  if (idx >= DIM_OUT * HDIM) return;
  int n = idx >> 9, k = idx & 511;
  Bt[idx] = f2bf(W[k * DIM_OUT + n] * scale[k]);
}

// ---------- bf16 MFMA GEMM: C[M,N] = A[M,K] @ Bt[N,K]^T (+bias) ----------
template<int OUTBF>
__global__ __launch_bounds__(256) void gemm_mfma(
    const unsigned short* __restrict__ A, const unsigned short* __restrict__ Bt,
    void* __restrict__ Cout, const float* __restrict__ bias,
    int M, int N, int K) {
  __shared__ unsigned short As[128 * LDK];
  __shared__ unsigned short Bs[128 * LDK];
  const int tid = threadIdx.x;
  const int lane = tid & 63, wid = tid >> 6;
  const int wr = wid >> 1, wc = wid & 1;
  const int l15 = lane & 15, lhi = lane >> 4;
  const int m0 = blockIdx.y * 128, n0 = blockIdx.x * 128;
  const int srow = tid >> 3;
  const int sc8 = (tid - srow) & 7;
  f32x4 acc[4][4];
#pragma unroll
  for (int i = 0; i < 4; ++i)
#pragma unroll
    for (int j = 0; j < 4; ++j) acc[i][j] = f32x4{0.f, 0.f, 0.f, 0.f};

  for (int k0 = 0; k0 < K; k0 += 64) {
    __syncthreads();
#pragma unroll
    for (int p = 0; p < 4; ++p) {
      int row = p * 32 + srow;
      us8 va = {0, 0, 0, 0, 0, 0, 0, 0};
      int gr = m0 + row;
      if (gr < M) va = *reinterpret_cast<const us8*>(&A[(size_t)gr * K + k0 + sc8 * 8]);
      *reinterpret_cast<us8*>(&As[row * LDK + sc8 * 8]) = va;
      us8 vb = {0, 0, 0, 0, 0, 0, 0, 0};
      int gn = n0 + row;
      if (gn < N) vb = *reinterpret_cast<const us8*>(&Bt[(size_t)gn * K + k0 + sc8 * 8]);
      *reinterpret_cast<us8*>(&Bs[row * LDK + sc8 * 8]) = vb;
    }
    __syncthreads();
#pragma unroll
    for (int kk = 0; kk < 2; ++kk) {
      bf16x8 af[4], bfr[4];
#pragma unroll
      for (int i = 0; i < 4; ++i)
        af[i] = *reinterpret_cast<const bf16x8*>(&As[(wr * 64 + i * 16 + l15) * LDK + kk * 32 + lhi * 8]);
#pragma unroll
      for (int j = 0; j < 4; ++j)
        bfr[j] = *reinterpret_cast<const bf16x8*>(&Bs[(wc * 64 + j * 16 + l15) * LDK + kk * 32 + lhi * 8]);
#pragma unroll
      for (int i = 0; i < 4; ++i)
#pragma unroll
        for (int j = 0; j < 4; ++j)
          acc[i][j] = __builtin_amdgcn_mfma_f32_16x16x32_bf16(af[i], bfr[j], acc[i][j], 0, 0, 0);
    }
  }
#pragma unroll
  for (int j = 0; j < 4; ++j) {
    int col = n0 + wc * 64 + j * 16 + l15;
    float bb = bias ? bias[col] : 0.f;
#pragma unroll
    for (int i = 0; i < 4; ++i) {
      f32x4 v = acc[i][j];
#pragma unroll
      for (int t = 0; t < 4; ++t) {
        int row = m0 + wr * 64 + i * 16 + lhi * 4 + t;
        if (row < M) {
          float o = v[t] + bb;
          if (OUTBF) ((unsigned short*)Cout)[(size_t)row * N + col] = f2bf(o);
          else       ((float*)Cout)[(size_t)row * N + col] = o;
        }
      }
    }
  }
}

// ---------- attn projections layer 1 (bf16 msg) ----------
__global__ __launch_bounds__(256) void attn1_kernel(
    const unsigned short* __restrict__ msg, const float* __restrict__ a_heads,
    float* __restrict__ asrc, float* __restrict__ adst, int Nn) {
  int lane = threadIdx.x & 63;
  int n = blockIdx.x * 4 + (threadIdx.x >> 6);
  if (n >= Nn) return;
  us8 v = *reinterpret_cast<const us8*>(&msg[(size_t)n * HDIM + lane * 8]);
  int h = lane >> 3, p0 = (lane & 7) * 8;
  float s = 0.f, d = 0.f;
#pragma unroll
  for (int j = 0; j < 8; ++j) {
    float f = bf2f(v[j]);
    s = fmaf(f, a_heads[h * 128 + p0 + j], s);
    d = fmaf(f, a_heads[h * 128 + 64 + p0 + j], d);
  }
  s += __shfl_xor(s, 1, 64); s += __shfl_xor(s, 2, 64); s += __shfl_xor(s, 4, 64);
  d += __shfl_xor(d, 1, 64); d += __shfl_xor(d, 2, 64); d += __shfl_xor(d, 4, 64);
  if ((lane & 7) == 0) { asrc[n * 8 + h] = s; adst[n * 8 + h] = d; }
}

// ---------- attn projections layer 2 (bf16 msg) ----------
__global__ __launch_bounds__(256) void attn2_kernel(
    const unsigned short* __restrict__ msg, const float* __restrict__ a_out,
    float* __restrict__ asrc, float* __restrict__ adst, int Nn) {
  int lane = threadIdx.x & 63;
  int n = blockIdx.x * 4 + (threadIdx.x >> 6);
  if (n >= Nn) return;
  us2 v = *reinterpret_cast<const us2*>(&msg[(size_t)n * 128 + lane * 2]);
  float f0 = bf2f(v[0]), f1 = bf2f(v[1]);
  float s = f0 * a_out[2 * lane] + f1 * a_out[2 * lane + 1];
  float d = f0 * a_out[128 + 2 * lane] + f1 * a_out[128 + 2 * lane + 1];
#pragma unroll
  for (int off = 32; off; off >>= 1) {
    s += __shfl_xor(s, off, 64);
    d += __shfl_xor(d, off, 64);
  }
  if (lane == 0) { asrc[n] = s; adst[n] = d; }
}

// ---------- CSR: histogram ----------
__global__ void hist_kernel(const int* __restrict__ edst, int* __restrict__ counts, int E) {
  for (int e = blockIdx.x * blockDim.x + threadIdx.x; e < E; e += gridDim.x * blockDim.x)
    atomicAdd(&counts[edst[e]], 1);
}

// ---------- CSR: 3-phase scan (1024 elems/block) ----------
__global__ __launch_bounds__(256) void scan1_kernel(
    const int* __restrict__ counts, int* __restrict__ rowptr, int* __restrict__ bsum, int n) {
  __shared__ int wsum[4];
  int b0 = blockIdx.x * 1024;
  int t = threadIdx.x;
  int lane = t & 63, w = t >> 6;
  int v[4]; int s = 0;
#pragma unroll
  for (int i = 0; i < 4; ++i) {
    int idx = b0 + t * 4 + i;
    v[i] = (idx < n) ? counts[idx] : 0;
    s += v[i];
  }
  int x = s;
#pragma unroll
  for (int off = 1; off < 64; off <<= 1) {
    int y = __shfl_up(x, off, 64);
    if (lane >= off) x += y;
  }
  if (lane == 63) wsum[w] = x;
  __syncthreads();
  int wof = 0;
  for (int i = 0; i < w; ++i) wof += wsum[i];
  int run = wof + x - s;   // exclusive prefix of this thread's 4
#pragma unroll
  for (int i = 0; i < 4; ++i) {
    int idx = b0 + t * 4 + i;
    if (idx < n) rowptr[idx] = run;
    run += v[i];
  }
  if (t == 255) bsum[blockIdx.x] = wof + x;
}

__global__ void scan2_kernel(int* __restrict__ bsum, int nb) {  // 1 block, 64 threads; nb<=64
  int t = threadIdx.x;
  int v = (t < nb) ? bsum[t] : 0;
  int x = v;
#pragma unroll
  for (int off = 1; off < 64; off <<= 1) {
    int y = __shfl_up(x, off, 64);
    if (t >= off) x += y;
  }
  if (t < nb) bsum[t] = x - v;   // exclusive
}

__global__ void scan3_kernel(int* __restrict__ rowptr, const int* __restrict__ bsum, int n) {
  int i = blockIdx.x * 256 + threadIdx.x;
  if (i < n) rowptr[i] += bsum[i >> 10];
  else if (i == n) rowptr[n] = N_EDGES;
}

// ---------- fused scatter + layer-1 max partials ----------
__global__ __launch_bounds__(256) void scatter_max1_kernel(
    const int* __restrict__ esrc, const int* __restrict__ edst,
    const float* __restrict__ asrc, const float* __restrict__ adst,
    const int* __restrict__ rowptr, int* __restrict__ cursor,
    int* __restrict__ colsrc, float* __restrict__ part, int E) {
  float m[8];
#pragma unroll
  for (int h = 0; h < 8; ++h) m[h] = -3.4e38f;
  for (int e = blockIdx.x * blockDim.x + threadIdx.x; e < E; e += gridDim.x * blockDim.x) {
    int s = esrc[e], d = edst[e];
    int pos = rowptr[d] + atomicAdd(&cursor[d], 1);
    colsrc[pos] = s;
    float4 s0 = *reinterpret_cast<const float4*>(&asrc[(size_t)s * 8]);
    float4 s1 = *reinterpret_cast<const float4*>(&asrc[(size_t)s * 8 + 4]);
    float4 d0 = *reinterpret_cast<const float4*>(&adst[(size_t)d * 8]);
    float4 d1 = *reinterpret_cast<const float4*>(&adst[(size_t)d * 8 + 4]);
    float xs[8] = {s0.x + d0.x, s0.y + d0.y, s0.z + d0.z, s0.w + d0.w,
                   s1.x + d1.x, s1.y + d1.y, s1.z + d1.z, s1.w + d1.w};
#pragma unroll
    for (int h = 0; h < 8; ++h) m[h] = fmaxf(m[h], leaky(xs[h]));
  }
#pragma unroll
  for (int h = 0; h < 8; ++h)
#pragma unroll
    for (int off = 32; off; off >>= 1) m[h] = fmaxf(m[h], __shfl_xor(m[h], off, 64));
  __shared__ float sm[4][8];
  int wv = threadIdx.x >> 6, ln = threadIdx.x & 63;
  if (ln == 0)
#pragma unroll
    for (int h = 0; h < 8; ++h) sm[wv][h] = m[h];
  __syncthreads();
  if (threadIdx.x < 8) {
    int h = threadIdx.x;
    part[blockIdx.x * 8 + h] =
        fmaxf(fmaxf(sm[0][h], sm[1][h]), fmaxf(sm[2][h], sm[3][h]));
  }
}

__global__ void max1_final_kernel(const float* __restrict__ part, float* __restrict__ maxv, int nblk) {
  int t = threadIdx.x;
  int h = t & 7, k = t >> 3;
  float m = -3.4e38f;
  for (int i = k; i < nblk; i += 8) m = fmaxf(m, part[i * 8 + h]);
  m = fmaxf(m, __shfl_xor(m, 8, 64));
  m = fmaxf(m, __shfl_xor(m, 16, 64));
  m = fmaxf(m, __shfl_xor(m, 32, 64));
  if (t < 8) maxv[t] = m;
}

// ---------- layer-2 max, two-stage ----------
__global__ __launch_bounds__(256) void max2_part_kernel(
    const int* __restrict__ esrc, const int* __restrict__ edst,
    const float* __restrict__ asrc, const float* __restrict__ adst,
    float* __restrict__ part, int E) {
  float m = -3.4e38f;
  for (int e = blockIdx.x * blockDim.x + threadIdx.x; e < E; e += gridDim.x * blockDim.x) {
    float x = asrc[esrc[e]] + adst[edst[e]];
    m = fmaxf(m, leaky(x));
  }
#pragma unroll
  for (int off = 32; off; off >>= 1) m = fmaxf(m, __shfl_xor(m, off, 64));
  __shared__ float sm[4];
  int wv = threadIdx.x >> 6, ln = threadIdx.x & 63;
  if (ln == 0) sm[wv] = m;
  __syncthreads();
  if (threadIdx.x == 0)
    part[blockIdx.x] = fmaxf(fmaxf(sm[0], sm[1]), fmaxf(sm[2], sm[3]));
}

__global__ void max2_final_kernel(const float* __restrict__ part, float* __restrict__ maxv, int nblk) {
  int t = threadIdx.x;
  float m = -3.4e38f;
  for (int i = t; i < nblk; i += 64) m = fmaxf(m, part[i]);
#pragma unroll
  for (int off = 32; off; off >>= 1) m = fmaxf(m, __shfl_xor(m, off, 64));
  if (t == 0) maxv[0] = m;
}

// ---------- layer-1 aggregation (bf16 gather, fused denom, unroll 4) ----------
__global__ __launch_bounds__(128) void agg1_kernel(
    const unsigned short* __restrict__ msg, const float* __restrict__ asrc,
    const float* __restrict__ adst, const float* __restrict__ maxv,
    const int* __restrict__ rowptr, const int* __restrict__ colsrc,
    unsigned short* __restrict__ out) {
  int n = blockIdx.x;
  int tid = threadIdx.x;
  __shared__ int s_sh[64];
  __shared__ float coef_sh[64][8];
  __shared__ float hdr[16];
  if (tid < 8) {
    hdr[tid] = maxv[tid];
    hdr[8 + tid] = adst[(size_t)n * 8 + tid];
  }
  __syncthreads();
  const int h = tid >> 4;
  const int e0 = rowptr[n], e1 = rowptr[n + 1];
  float4 acc = make_float4(0.f, 0.f, 0.f, 0.f);
  float dsum = 0.f;
  for (int base = e0; base < e1; base += 64) {
    int cnt = min(64, e1 - base);
    __syncthreads();
#pragma unroll
    for (int q = 0; q < 4; ++q) {
      int slot = q * 128 + tid;
      int el = slot >> 3, hh = slot & 7;
      if (el < cnt) {
        int s = colsrc[base + el];
        if (hh == 0) s_sh[el] = s;
        float x = asrc[(size_t)s * 8 + hh] + hdr[8 + hh];
        x = x >= 0.f ? x : 0.2f * x;
        coef_sh[el][hh] = __expf(x - hdr[hh]);
      }
    }
    __syncthreads();
    int e = 0;
    for (; e + 4 <= cnt; e += 4) {
      int sA = s_sh[e], sB = s_sh[e + 1], sC = s_sh[e + 2], sD = s_sh[e + 3];
      us4 ma = *reinterpret_cast<const us4*>(&msg[(size_t)sA * HDIM + tid * 4]);
      us4 mb = *reinterpret_cast<const us4*>(&msg[(size_t)sB * HDIM + tid * 4]);
      us4 mc = *reinterpret_cast<const us4*>(&msg[(size_t)sC * HDIM + tid * 4]);
      us4 md = *reinterpret_cast<const us4*>(&msg[(size_t)sD * HDIM + tid * 4]);
      float ca = coef_sh[e][h], cb = coef_sh[e + 1][h];
      float cc = coef_sh[e + 2][h], cd = coef_sh[e + 3][h];
      dsum += (ca + cb) + (cc + cd);
      acc.x = fmaf(bf2f(ma[0]), ca, acc.x); acc.y = fmaf(bf2f(ma[1]), ca, acc.y);
      acc.z = fmaf(bf2f(ma[2]), ca, acc.z); acc.w = fmaf(bf2f(ma[3]), ca, acc.w);
      acc.x = fmaf(bf2f(mb[0]), cb, acc.x); acc.y = fmaf(bf2f(mb[1]), cb, acc.y);
      acc.z = fmaf(bf2f(mb[2]), cb, acc.z); acc.w = fmaf(bf2f(mb[3]), cb, acc.w);
      acc.x = fmaf(bf2f(mc[0]), cc, acc.x); acc.y = fmaf(bf2f(mc[1]), cc, acc.y);
      acc.z = fmaf(bf2f(mc[2]), cc, acc.z); acc.w = fmaf(bf2f(mc[3]), cc, acc.w);
      acc.x = fmaf(bf2f(md[0]), cd, acc.x); acc.y = fmaf(bf2f(md[1]), cd, acc.y);
      acc.z = fmaf(bf2f(md[2]), cd, acc.z); acc.w = fmaf(bf2f(md[3]), cd, acc.w);
    }
    for (; e < cnt; ++e) {
      int s = s_sh[e];
      float c = coef_sh[e][h];
      dsum += c;
      us4 m4 = *reinterpret_cast<const us4*>(&msg[(size_t)s * HDIM + tid * 4]);
      acc.x = fmaf(bf2f(m4[0]), c, acc.x); acc.y = fmaf(bf2f(m4[1]), c, acc.y);
      acc.z = fmaf(bf2f(m4[2]), c, acc.z); acc.w = fmaf(bf2f(m4[3]), c, acc.w);
    }
  }
  float inv = 1.0f / (dsum + 1e-10f);
  us4 o;
  o[0] = f2bf(acc.x * inv); o[1] = f2bf(acc.y * inv);
  o[2] = f2bf(acc.z * inv); o[3] = f2bf(acc.w * inv);
  *reinterpret_cast<us4*>(&out[(size_t)n * HDIM + tid * 4]) = o;
}

// ---------- layer-2 aggregation: wave-per-node, shfl-broadcast coefs, unroll 4 ----------
__global__ __launch_bounds__(256) void agg2_kernel(
    const unsigned short* __restrict__ msg, const float* __restrict__ asrc,
    const float* __restrict__ adst, const float* __restrict__ maxv,
    const int* __restrict__ rowptr, const int* __restrict__ colsrc,
    float* __restrict__ out) {
  int wv = threadIdx.x >> 6, ln = threadIdx.x & 63;
  int n = blockIdx.x * 4 + wv;              // N_NODES % 4 == 0
  float M = maxv[0];
  float ad = adst[n];
  int e0 = rowptr[n], e1 = rowptr[n + 1];
  float a0 = 0.f, a1 = 0.f, ds = 0.f;
  for (int base = e0; base < e1; base += 64) {
    int cnt = min(64, e1 - base);
    int s_reg = 0; float c_reg = 0.f;
    if (ln < cnt) {
      s_reg = colsrc[base + ln];
      float x = asrc[s_reg] + ad;
      x = x >= 0.f ? x : 0.2f * x;
      c_reg = __expf(x - M);
    }
    int e = 0;
    for (; e + 4 <= cnt; e += 4) {
      int s0 = __shfl(s_reg, e, 64),     s1 = __shfl(s_reg, e + 1, 64);
      int s2 = __shfl(s_reg, e + 2, 64), s3 = __shfl(s_reg, e + 3, 64);
      float c0 = __shfl(c_reg, e, 64),     c1 = __shfl(c_reg, e + 1, 64);
      float c2 = __shfl(c_reg, e + 2, 64), c3 = __shfl(c_reg, e + 3, 64);
      us2 m0 = *reinterpret_cast<const us2*>(&msg[(size_t)s0 * 128 + 2 * ln]);
      us2 m1 = *reinterpret_cast<const us2*>(&msg[(size_t)s1 * 128 + 2 * ln]);
      us2 m2 = *reinterpret_cast<const us2*>(&msg[(size_t)s2 * 128 + 2 * ln]);
      us2 m3 = *reinterpret_cast<const us2*>(&msg[(size_t)s3 * 128 + 2 * ln]);
      ds += (c0 + c1) + (c2 + c3);
      a0 = fmaf(bf2f(m0[0]), c0, a0); a1 = fmaf(bf2f(m0[1]), c0, a1);
      a0 = fmaf(bf2f(m1[0]), c1, a0); a1 = fmaf(bf2f(m1[1]), c1, a1);
      a0 = fmaf(bf2f(m2[0]), c2, a0); a1 = fmaf(bf2f(m2[1]), c2, a1);
      a0 = fmaf(bf2f(m3[0]), c3, a0); a1 = fmaf(bf2f(m3[1]), c3, a1);
    }
    for (; e < cnt; ++e) {
      int s = __shfl(s_reg, e, 64);
      float c = __shfl(c_reg, e, 64);
      us2 m = *reinterpret_cast<const us2*>(&msg[(size_t)s * 128 + 2 * ln]);
      ds += c;
      a0 = fmaf(bf2f(m[0]), c, a0);
      a1 = fmaf(bf2f(m[1]), c, a1);
    }
  }
  float inv = 1.0f / (ds + 1e-10f);
  float2 r; r.x = a0 * inv; r.y = a1 * inv;
  *reinterpret_cast<float2*>(&out[(size_t)n * 128 + 2 * ln]) = r;
}

// ---------- BN statistics ----------
__global__ void colstats_kernel(const float* __restrict__ X, float* __restrict__ sums,
                                float* __restrict__ sqs, int M, int C, int rowsPerBlock) {
  int c = blockIdx.x * blockDim.x + threadIdx.x;
  if (c >= C) return;
  int r0 = blockIdx.y * rowsPerBlock;
  int r1 = min(M, r0 + rowsPerBlock);
  float s = 0.f, s2 = 0.f;
  for (int r = r0; r < r1; ++r) {
    float v = X[(size_t)r * C + c];
    s += v; s2 = fmaf(v, v, s2);
  }
  atomicAdd(&sums[c], s);
  atomicAdd(&sqs[c], s2);
}

__global__ void colstats_bf_kernel(const unsigned short* __restrict__ X, float* __restrict__ sums,
                                   float* __restrict__ sqs, int M, int C, int rowsPerBlock) {
  int c = blockIdx.x * blockDim.x + threadIdx.x;
  if (c >= C) return;
  int r0 = blockIdx.y * rowsPerBlock;
  int r1 = min(M, r0 + rowsPerBlock);
  float s = 0.f, s2 = 0.f;
  for (int r = r0; r < r1; ++r) {
    float v = bf2f(X[(size_t)r * C + c]);
    s += v; s2 = fmaf(v, v, s2);
  }
  atomicAdd(&sums[c], s);
  atomicAdd(&sqs[c], s2);
}

__global__ void bnparams_kernel(const float* __restrict__ sums, const float* __restrict__ sqs,
                                const float* __restrict__ gamma, const float* __restrict__ beta,
                                float* __restrict__ scale, float* __restrict__ shift,
                                int C, float invM) {
  int c = blockIdx.x * blockDim.x + threadIdx.x;
  if (c >= C) return;
  float mean = sums[c] * invM;
  float var = sqs[c] * invM - mean * mean;
  float inv = rsqrtf(var + 1e-5f);
  float sc = gamma[c] * inv;
  scale[c] = sc;
  shift[c] = beta[c] - mean * sc;
}

__global__ void bias2_kernel(const float* __restrict__ W, const float* __restrict__ shift,
                             float* __restrict__ bias2) {
  int j = threadIdx.x;
  if (j >= DIM_OUT) return;
  float s = 0.f;
  for (int c = 0; c < HDIM; ++c) s = fmaf(shift[c], W[c * DIM_OUT + j], s);
  bias2[j] = s;
}

// ---------- final: BN(out2) + residual ----------
__global__ void final_kernel(float* __restrict__ out, const float* __restrict__ resid,
                             const float* __restrict__ scale, const float* __restrict__ shift,
                             int total) {
  for (int i = blockIdx.x * blockDim.x + threadIdx.x; i < total; i += gridDim.x * blockDim.x) {
    int c = i & 127;
    out[i] = fmaf(out[i], scale[c], shift[c]) + resid[i];
  }
}

// ==================== host ====================
extern "C" void kernel_launch(void* const* d_in, const int* in_sizes, int n_in,
                              void* d_out, int out_size, void* d_ws, size_t ws_size,
                              hipStream_t stream) {
  const float* feat    = (const float*)d_in[0];
  const int*   edges   = (const int*)d_in[1];
  const int*   esrc    = edges;
  const int*   edst    = edges + N_EDGES;
  const float* W_heads = (const float*)d_in[2];
  const float* a_heads = (const float*)d_in[3];
  const float* gamma_h = (const float*)d_in[4];
  const float* beta_h  = (const float*)d_in[5];
  const float* W_out   = (const float*)d_in[6];
  const float* a_out   = (const float*)d_in[7];
  const float* gamma_o = (const float*)d_in[8];
  const float* beta_o  = (const float*)d_in[9];
  const float* W_res   = (const float*)d_in[10];
  const float* b_res   = (const float*)d_in[11];
  float* out = (float*)d_out;

  char* ws = (char*)d_ws;
  size_t off = 0;
  auto alloc = [&](size_t bytes) {
    void* p = ws + off;
    off = (off + bytes + 255) & ~(size_t)255;
    return p;
  };
  unsigned short* msg1    = (unsigned short*)alloc((size_t)N_NODES * HDIM * 2);  // reused as msg2
  unsigned short* out1_bf = (unsigned short*)alloc((size_t)N_NODES * HDIM * 2);
  unsigned short* feat_bf = (unsigned short*)alloc((size_t)N_NODES * DIM_IN * 2);
  float*    resid  = (float*)alloc((size_t)N_NODES * DIM_OUT * 4);
  float*    asrc1  = (float*)alloc((size_t)N_NODES * NHEADS * 4); // reused as asrc2
  float*    adst1  = (float*)alloc((size_t)N_NODES * NHEADS * 4); // reused as adst2
  int*      counts = (int*)alloc((size_t)N_NODES * 4);
  int*      cursor = (int*)alloc((size_t)N_NODES * 4);
  int*      rowptr = (int*)alloc((size_t)(N_NODES + 1) * 4);
  int*      colsrc = (int*)alloc((size_t)N_EDGES * 4);
  int*      bsum   = (int*)alloc(64 * 4);
  float*    part   = (float*)alloc((size_t)SMBLK * 8 * 4);
  float*    maxv1  = (float*)alloc(8 * 4);
  float*    maxv2  = (float*)alloc(4);
  float*    colsum = (float*)alloc(HDIM * 4);
  float*    colsq  = (float*)alloc(HDIM * 4);
  float*    scale1 = (float*)alloc(HDIM * 4);
  float*    shift1 = (float*)alloc(HDIM * 4);
  float*    scale2 = (float*)alloc(DIM_OUT * 4);
  float*    shift2 = (float*)alloc(DIM_OUT * 4);
  unsigned short* Bt1 = (unsigned short*)alloc((size_t)HDIM * DIM_IN * 2);
  unsigned short* Bt2 = (unsigned short*)alloc((size_t)DIM_OUT * HDIM * 2);
  unsigned short* Btr = (unsigned short*)alloc((size_t)DIM_OUT * DIM_IN * 2);
  float*    bias2  = (float*)alloc(DIM_OUT * 4);
  unsigned short* msg2 = msg1;
  float* asrc2 = asrc1; float* adst2 = adst1;
  (void)n_in; (void)in_sizes; (void)out_size; (void)ws_size;

  hipMemsetAsync(counts, 0, (size_t)N_NODES * 4, stream);
  hipMemsetAsync(cursor, 0, (size_t)N_NODES * 4, stream);
  hipMemsetAsync(colsum, 0, HDIM * 4, stream);
  hipMemsetAsync(colsq, 0, HDIM * 4, stream);

  // ---- prep (cvt + packs fused) ----
  prep_kernel<<<6570, 256, 0, stream>>>(feat, W_heads, W_res, feat_bf, Bt1, Btr);

  // ---- layer 1 ----
  dim3 g1(HDIM / 128, (N_NODES + 127) / 128);
  gemm_mfma<1><<<g1, 256, 0, stream>>>(feat_bf, Bt1, msg1, nullptr, N_NODES, HDIM, DIM_IN);
  attn1_kernel<<<(N_NODES + 3) / 4, 256, 0, stream>>>(msg1, a_heads, asrc1, adst1, N_NODES);

  hist_kernel<<<2048, 256, 0, stream>>>(edst, counts, N_EDGES);
  int nsb = (N_NODES + 1023) / 1024;   // 49
  scan1_kernel<<<nsb, 256, 0, stream>>>(counts, rowptr, bsum, N_NODES);
  scan2_kernel<<<1, 64, 0, stream>>>(bsum, nsb);
  scan3_kernel<<<(N_NODES + 256) / 256, 256, 0, stream>>>(rowptr, bsum, N_NODES);

  scatter_max1_kernel<<<SMBLK, 256, 0, stream>>>(esrc, edst, asrc1, adst1, rowptr,
                                                 cursor, colsrc, part, N_EDGES);
  max1_final_kernel<<<1, 64, 0, stream>>>(part, maxv1, SMBLK);
  agg1_kernel<<<N_NODES, 128, 0, stream>>>(msg1, asrc1, adst1, maxv1, rowptr, colsrc, out1_bf);

  colstats_bf_kernel<<<dim3(HDIM / 128, 98), 128, 0, stream>>>(out1_bf, colsum, colsq, N_NODES, HDIM, 512);
  bnparams_kernel<<<(HDIM + 127) / 128, 128, 0, stream>>>(colsum, colsq, gamma_h, beta_h,
                                                          scale1, shift1, HDIM, 1.0f / N_NODES);
  foldw2_kernel<<<(DIM_OUT * HDIM + 255) / 256, 256, 0, stream>>>(W_out, scale1, Bt2);
  bias2_kernel<<<1, 128, 0, stream>>>(W_out, shift1, bias2);

  // ---- layer 2 ----
  dim3 g2(DIM_OUT / 128, (N_NODES + 127) / 128);
  gemm_mfma<1><<<g2, 256, 0, stream>>>(out1_bf, Bt2, msg2, bias2, N_NODES, DIM_OUT, HDIM);
  attn2_kernel<<<(N_NODES + 3) / 4, 256, 0, stream>>>(msg2, a_out, asrc2, adst2, N_NODES);

  max2_part_kernel<<<MAXBLK, 256, 0, stream>>>(esrc, edst, asrc2, adst2, part, N_EDGES);
  max2_final_kernel<<<1, 64, 0, stream>>>(part, maxv2, MAXBLK);
  agg2_kernel<<<N_NODES / 4, 256, 0, stream>>>(msg2, asrc2, adst2, maxv2, rowptr, colsrc, out);

  // residual GEMM (bf16 MFMA, fp32 out)
  gemm_mfma<0><<<g2, 256, 0, stream>>>(feat_bf, Btr, resid, b_res, N_NODES, DIM_OUT, DIM_IN);

  // layer-2 BN + residual
  hipMemsetAsync(colsum, 0, HDIM * 4, stream);
  hipMemsetAsync(colsq, 0, HDIM * 4, stream);
  colstats_kernel<<<dim3(1, 98), 128, 0, stream>>>(out, colsum, colsq, N_NODES, DIM_OUT, 512);
  bnparams_kernel<<<1, 128, 0, stream>>>(colsum, colsq, gamma_o, beta_o,
                                         scale2, shift2, DIM_OUT, 1.0f / N_NODES);
  final_kernel<<<2048, 256, 0, stream>>>(out, resid, scale2, shift2, N_NODES * DIM_OUT);
}